// Round 5
// baseline (1988.482 us; speedup 1.0000x reference)
//
#include <hip/hip_runtime.h>
#include <hip/hip_fp16.h>
#include <math.h>

// Round 5: round 4 structure unchanged; fix the REAL blocker. Rounds 2-4 all
// spilled the fp16 weight array because clang's occupancy heuristic targeted
// 8 waves/EU (64-VGPR cap) despite __launch_bounds__(.,4) (which only sets a
// MINIMUM waves/EU -> max-VGPR bound; compiler may still aim higher).
// amdgpu_waves_per_eu(4,4) PINS 4 waves/EU: hard 128-VGPR budget, no 8-wave
// target to chase -> w[64] (64 VGPR) + ~40 working set stays resident.
// Evidence of spill (round 4): VGPR_Count=64, FETCH 4.43GB (scratch re-read),
// WRITE 105MB = 33MB out + 67MB one-time scratch write (256KB x 256 blocks).

namespace {

constexpr int S_LEN = 128;
constexpr int V_N   = 256;

__device__ __forceinline__ float sigmoidf_(float x) {
    return 1.0f / (1.0f + expf(-x));
}

__global__ void __launch_bounds__(1024)
__attribute__((amdgpu_waves_per_eu(4, 4)))
scan_kernel(
    const float* __restrict__ av_g,   // [S,B,V]
    const float* __restrict__ xn_g,
    const float* __restrict__ xv_g,
    const float* __restrict__ yn_g,
    const float* __restrict__ yv_g,
    const float* __restrict__ sv_g,   // [32,256]
    const float* __restrict__ sw_g,   // [256,512]
    const float* __restrict__ snw_g,  // [256,2]
    const float* __restrict__ def_g,  // [4,256]
    const float* __restrict__ vnw_g,  // [6,3]
    float* __restrict__ out)          // [B,S,V]
{
    const int b    = blockIdx.x;
    const int t    = threadIdx.x;     // 0..1023
    const int wave = t >> 6;
    const int lane = t & 63;
    const int c    = t & 255;         // choice row
    const int j    = t >> 8;          // quarter 0..3 (uniform per wave)
    constexpr float EPS = 1e-8f;

    __shared__ __align__(16) float rs_lds[V_N];
    __shared__ __align__(16) float val_lds[V_N];
    __shared__ float partials[4][256];    // [quarter][row]
    __shared__ float wsum[4][8];
    __shared__ float gw[32];
    __shared__ float sv_lds[32][V_N];
    __shared__ float nwv_lds[18];
    __shared__ float def_lds[4][V_N];
    __shared__ float rowp_lds[4][256];    // invw0, invw1, nws0, nws1 per row

    // ---- one-time setup ----
    for (int i = t; i < 32 * V_N; i += 1024) sv_lds[i >> 8][i & 255] = sv_g[i];
    def_lds[t >> 8][t & 255] = def_g[t];          // t spans exactly 4*256
    if (t < 18) nwv_lds[t] = sigmoidf_(vnw_g[t]);

    // thread (c,j) holds row c, float elements [j*128, j*128+128) of the
    // 512-float row (k=0 occupies [0,256) ~ rs; k=1 occupies [256,512) ~ val).
    const float4* wsrc = reinterpret_cast<const float4*>(
        sw_g + (size_t)c * 512 + (size_t)j * 128);
    __half2 w[64];                        // 64 VGPRs of fp16 weights
    float nsq = 0.f;
#pragma unroll
    for (int i = 0; i < 32; ++i) {
        const float4 a = wsrc[i];
        const __half2 h0 = __floats2half2_rn(a.x, a.y);
        const __half2 h1 = __floats2half2_rn(a.z, a.w);
        w[2 * i]     = h0;
        w[2 * i + 1] = h1;
        float2 f;
        f = __half22float2(h0); nsq += f.x * f.x + f.y * f.y;
        f = __half22float2(h1); nsq += f.x * f.x + f.y * f.y;
    }
    partials[j][c] = nsq;
    __syncthreads();

    if (t < 256) {
        rowp_lds[0][t] = 1.0f / fmaxf(sqrtf(partials[0][t] + partials[1][t]), EPS);
        rowp_lds[1][t] = 1.0f / fmaxf(sqrtf(partials[2][t] + partials[3][t]), EPS);
        rowp_lds[2][t] = sigmoidf_(snw_g[2 * t]);
        rowp_lds[3][t] = sigmoidf_(snw_g[2 * t + 1]);
    }

    // wave-uniform segment pointer for phase 3 (j uniform per wave)
    const float4* seg4 = reinterpret_cast<const float4*>(
        (j < 2) ? (rs_lds + (j << 7)) : (val_lds + ((j - 2) << 7)));

    float rs = 1e-6f;
    float av = 0.f, xn = 0.f, xv = 0.f, yn = 0.f, yv = 0.f;
    if (t < 256) {
        const size_t base0 = (size_t)b * 256 + t;
        av = av_g[base0]; xn = xn_g[base0]; xv = xv_g[base0];
        yn = yn_g[base0]; yv = yv_g[base0];
    }

    for (int s = 0; s < S_LEN; ++s) {
        // ---- phase 1: 7 block reductions over V (t<256) ----
        if (t < 256) {
            float q0 = av * xn, q1 = av * yn, q2 = xn * yn;
            float q3 = av * av, q4 = xn * xn, q5 = yn * yn, q6 = rs * rs;
#pragma unroll
            for (int off = 32; off >= 1; off >>= 1) {
                q0 += __shfl_xor(q0, off);
                q1 += __shfl_xor(q1, off);
                q2 += __shfl_xor(q2, off);
                q3 += __shfl_xor(q3, off);
                q4 += __shfl_xor(q4, off);
                q5 += __shfl_xor(q5, off);
                q6 += __shfl_xor(q6, off);
            }
            if (lane == 0) {
                wsum[wave][0] = q0; wsum[wave][1] = q1; wsum[wave][2] = q2;
                wsum[wave][3] = q3; wsum[wave][4] = q4; wsum[wave][5] = q5;
                wsum[wave][6] = q6;
            }
        }
        __syncthreads();   // sync1

        float inv_rs = 0.f;
        // ---- phase 2: cs, var-choice blend, stage rs/val (t<256) ----
        if (t < 256) {
            float axn = 0, ayn = 0, xny = 0, naa = 0, nxx = 0, nyy = 0, nrs = 0;
#pragma unroll
            for (int w4 = 0; w4 < 4; ++w4) {
                axn += wsum[w4][0]; ayn += wsum[w4][1]; xny += wsum[w4][2];
                naa += wsum[w4][3]; nxx += wsum[w4][4]; nyy += wsum[w4][5];
                nrs += wsum[w4][6];
            }
            const float na = fmaxf(sqrtf(naa), EPS);
            const float nx = fmaxf(sqrtf(nxx), EPS);
            const float ny = fmaxf(sqrtf(nyy), EPS);
            float csarr[3];
            csarr[0] = axn / (na * nx);
            csarr[1] = ayn / (na * ny);
            csarr[2] = xny / (nx * ny);
            inv_rs = 1.0f / fmaxf(sqrtf(nrs), EPS);

            float vc[6];
#pragma unroll
            for (int jj = 0; jj < 6; ++jj) {
                float p = 1.0f;
#pragma unroll
                for (int k = 0; k < 3; ++k) {
                    const float a   = nwv_lds[jj * 3 + k];
                    const float csk = csarr[k];
                    p = p * (a * csk + (1.0f - a) * (1.0f - csk));
                }
                vc[jj] = p;
            }
            const float val = vc[0] * xv + vc[1] * yv
                            + vc[2] * def_lds[0][t] + vc[3] * def_lds[1][t]
                            + vc[4] * def_lds[2][t] + vc[5] * def_lds[3][t];
            rs_lds[t]  = rs;
            val_lds[t] = val;
            float qv = val * val;
#pragma unroll
            for (int off = 32; off >= 1; off >>= 1) qv += __shfl_xor(qv, off);
            if (lane == 0) wsum[wave][7] = qv;
        }
        __syncthreads();   // sync2

        // ---- phase 3: quarter-row dots (all 1024 threads) ----
        // prefetch next step's inputs under the dot compute (t<256)
        float avn = av, xnn = xn, xvn = xv, ynn = yn, yvn = yv;
        if (t < 256) {
            const int sn = (s + 1 < S_LEN) ? s + 1 : s;
            const size_t basen = (size_t)sn * (256 * 256) + (size_t)b * 256 + t;
            avn = av_g[basen]; xnn = xn_g[basen]; xvn = xv_g[basen];
            ynn = yn_g[basen]; yvn = yv_g[basen];
        }
        float dA = 0.f, dB = 0.f, dC = 0.f, dD = 0.f;
#pragma unroll
        for (int i = 0; i < 32; i += 2) {
            const float4 r0 = seg4[i];
            const float4 r1 = seg4[i + 1];
            const float2 a0 = __half22float2(w[2 * i]);
            const float2 a1 = __half22float2(w[2 * i + 1]);
            const float2 b0 = __half22float2(w[2 * i + 2]);
            const float2 b1 = __half22float2(w[2 * i + 3]);
            dA += a0.x * r0.x + a0.y * r0.y;
            dB += a1.x * r0.z + a1.y * r0.w;
            dC += b0.x * r1.x + b0.y * r1.y;
            dD += b1.x * r1.z + b1.y * r1.w;
        }
        partials[j][c] = (dA + dB) + (dC + dD);
        __syncthreads();   // sync3

        // ---- phase 3b: combine quarters, NAND, redundancy-reduce (t<256) ----
        if (t < 256) {
            const float inv_val = 1.0f / fmaxf(sqrtf(wsum[0][7] + wsum[1][7] +
                                                     wsum[2][7] + wsum[3][7]), EPS);
            const float d0 = partials[0][t] + partials[1][t];
            const float d1 = partials[2][t] + partials[3][t];
            float c0 = d0 * inv_rs  * rowp_lds[0][t];
            float c1 = d1 * inv_val * rowp_lds[1][t];
            c0 = (c0 > 0.f) ? c0 : 0.01f * c0;   // leaky_relu
            c1 = (c1 > 0.f) ? c1 : 0.01f * c1;
            const float nw0 = rowp_lds[2][t];
            const float nw1 = rowp_lds[3][t];
            const float i0 = nw0 * c0 + (1.0f - nw0) * (1.0f - c0);
            const float i1 = nw1 * c1 + (1.0f - nw1) * (1.0f - c1);
            float choice = i0 * i1;
            choice += __shfl_xor(choice, 1);
            choice += __shfl_xor(choice, 2);
            choice += __shfl_xor(choice, 4);
            if ((t & 7) == 0) gw[t >> 3] = choice;
        }
        __syncthreads();   // sync4

        // ---- phase 4: new_rs, store, rotate prefetched inputs (t<256) ----
        if (t < 256) {
            float nrs_new = 0.f;
#pragma unroll
            for (int nc = 0; nc < 32; ++nc) nrs_new += sv_lds[nc][t] * gw[nc];
            rs = nrs_new;
            out[((size_t)b * S_LEN + s) * V_N + t] = rs;
            av = avn; xn = xnn; xv = xvn; yn = ynn; yv = yvn;
        }
        // LDS hazards: every buffer has >=2 barriers between write and reuse.
    }
}

} // namespace

extern "C" void kernel_launch(void* const* d_in, const int* in_sizes, int n_in,
                              void* d_out, int out_size, void* d_ws, size_t ws_size,
                              hipStream_t stream) {
    (void)in_sizes; (void)n_in; (void)d_ws; (void)ws_size; (void)out_size;
    const float* av  = (const float*)d_in[0];
    const float* xn  = (const float*)d_in[1];
    const float* xv  = (const float*)d_in[2];
    const float* yn  = (const float*)d_in[3];
    const float* yv  = (const float*)d_in[4];
    const float* sv  = (const float*)d_in[5];
    const float* sw  = (const float*)d_in[6];
    const float* snw = (const float*)d_in[7];
    const float* def = (const float*)d_in[8];
    const float* vnw = (const float*)d_in[9];
    scan_kernel<<<dim3(256), dim3(1024), 0, stream>>>(
        av, xn, xv, yn, yv, sv, sw, snw, def, vnw, (float*)d_out);
}

// Round 6
// 1979.186 us; speedup vs baseline: 1.0047x; 1.0047x over previous
//
#include <hip/hip_runtime.h>
#include <hip/hip_fp16.h>
#include <math.h>

// Round 6: rounds 2-5 all spilled the per-thread weight array NOT because of
// occupancy caps but because SROA never promoted the alloca: `w[2*i]` with a
// loop-variable index is unpromotable at the point SROA runs (before unroll),
// so the array lived in scratch from IR onward (VGPR_Count=64 while holding a
// "64-VGPR" array; waves_per_eu changed SGPRs but not VGPRs -> demand really
// was ~60). Fix: weights as 16 NAMED uint4 values (W0..W15, 8 fp16 each),
// accessed only via .x/.y/.z/.w in macro-unrolled code -> pure SSA, no alloca,
// scratch structurally impossible. Everything else as round 5.

namespace {

constexpr int S_LEN = 128;
constexpr int V_N   = 256;

__device__ __forceinline__ float sigmoidf_(float x) {
    return 1.0f / (1.0f + expf(-x));
}

__device__ __forceinline__ unsigned packh2(float x, float y, float& nsq) {
    const __half2 h = __floats2half2_rn(x, y);
    const float2 f = __half22float2(h);
    nsq += f.x * f.x + f.y * f.y;
    union { __half2 h2; unsigned u; } cvt;
    cvt.h2 = h;
    return cvt.u;
}

__device__ __forceinline__ float2 up2(unsigned u) {
    union { unsigned u; __half2 h2; } cvt;
    cvt.u = u;
    return __half22float2(cvt.h2);
}

#define PACKW(W, i0)                                   \
    do {                                               \
        const float4 a0 = wsrc[(i0)];                  \
        const float4 a1 = wsrc[(i0) + 1];              \
        W.x = packh2(a0.x, a0.y, nsq);                 \
        W.y = packh2(a0.z, a0.w, nsq);                 \
        W.z = packh2(a1.x, a1.y, nsq);                 \
        W.w = packh2(a1.z, a1.w, nsq);                 \
    } while (0)

#define DOTW(W, i0)                                    \
    do {                                               \
        const float4 r0 = seg4[(i0)];                  \
        const float4 r1 = seg4[(i0) + 1];              \
        float2 f;                                      \
        f = up2(W.x); dA += f.x * r0.x + f.y * r0.y;   \
        f = up2(W.y); dB += f.x * r0.z + f.y * r0.w;   \
        f = up2(W.z); dC += f.x * r1.x + f.y * r1.y;   \
        f = up2(W.w); dD += f.x * r1.z + f.y * r1.w;   \
    } while (0)

__global__ void __launch_bounds__(1024)
__attribute__((amdgpu_waves_per_eu(4, 4)))
scan_kernel(
    const float* __restrict__ av_g,   // [S,B,V]
    const float* __restrict__ xn_g,
    const float* __restrict__ xv_g,
    const float* __restrict__ yn_g,
    const float* __restrict__ yv_g,
    const float* __restrict__ sv_g,   // [32,256]
    const float* __restrict__ sw_g,   // [256,512]
    const float* __restrict__ snw_g,  // [256,2]
    const float* __restrict__ def_g,  // [4,256]
    const float* __restrict__ vnw_g,  // [6,3]
    float* __restrict__ out)          // [B,S,V]
{
    const int b    = blockIdx.x;
    const int t    = threadIdx.x;     // 0..1023
    const int wave = t >> 6;
    const int lane = t & 63;
    const int c    = t & 255;         // choice row
    const int j    = t >> 8;          // quarter 0..3 (uniform per wave)
    constexpr float EPS = 1e-8f;

    __shared__ __align__(16) float rs_lds[V_N];
    __shared__ __align__(16) float val_lds[V_N];
    __shared__ float partials[4][256];    // [quarter][row]
    __shared__ float wsum[4][8];
    __shared__ float gw[32];
    __shared__ float sv_lds[32][V_N];
    __shared__ float nwv_lds[18];
    __shared__ float def_lds[4][V_N];
    __shared__ float rowp_lds[4][256];    // invw0, invw1, nws0, nws1 per row

    // ---- one-time setup ----
    for (int i = t; i < 32 * V_N; i += 1024) sv_lds[i >> 8][i & 255] = sv_g[i];
    def_lds[t >> 8][t & 255] = def_g[t];          // t spans exactly 4*256
    if (t < 18) nwv_lds[t] = sigmoidf_(vnw_g[t]);

    // thread (c,j) holds row c, float elements [j*128, j*128+128) of the
    // 512-float row (k=0 occupies [0,256) ~ rs; k=1 occupies [256,512) ~ val).
    const float4* wsrc = reinterpret_cast<const float4*>(
        sw_g + (size_t)c * 512 + (size_t)j * 128);
    float nsq = 0.f;
    uint4 W0, W1, W2, W3, W4, W5, W6, W7, W8, W9, W10, W11, W12, W13, W14, W15;
    PACKW(W0, 0);   PACKW(W1, 2);   PACKW(W2, 4);   PACKW(W3, 6);
    PACKW(W4, 8);   PACKW(W5, 10);  PACKW(W6, 12);  PACKW(W7, 14);
    PACKW(W8, 16);  PACKW(W9, 18);  PACKW(W10, 20); PACKW(W11, 22);
    PACKW(W12, 24); PACKW(W13, 26); PACKW(W14, 28); PACKW(W15, 30);
    partials[j][c] = nsq;
    __syncthreads();

    if (t < 256) {
        rowp_lds[0][t] = 1.0f / fmaxf(sqrtf(partials[0][t] + partials[1][t]), EPS);
        rowp_lds[1][t] = 1.0f / fmaxf(sqrtf(partials[2][t] + partials[3][t]), EPS);
        rowp_lds[2][t] = sigmoidf_(snw_g[2 * t]);
        rowp_lds[3][t] = sigmoidf_(snw_g[2 * t + 1]);
    }

    // wave-uniform segment pointer for phase 3 (j uniform per wave)
    const float4* seg4 = reinterpret_cast<const float4*>(
        (j < 2) ? (rs_lds + (j << 7)) : (val_lds + ((j - 2) << 7)));

    float rs = 1e-6f;
    float av = 0.f, xn = 0.f, xv = 0.f, yn = 0.f, yv = 0.f;
    if (t < 256) {
        const size_t base0 = (size_t)b * 256 + t;
        av = av_g[base0]; xn = xn_g[base0]; xv = xv_g[base0];
        yn = yn_g[base0]; yv = yv_g[base0];
    }

    for (int s = 0; s < S_LEN; ++s) {
        // ---- phase 1: 7 block reductions over V (t<256) ----
        if (t < 256) {
            float q0 = av * xn, q1 = av * yn, q2 = xn * yn;
            float q3 = av * av, q4 = xn * xn, q5 = yn * yn, q6 = rs * rs;
#pragma unroll
            for (int off = 32; off >= 1; off >>= 1) {
                q0 += __shfl_xor(q0, off);
                q1 += __shfl_xor(q1, off);
                q2 += __shfl_xor(q2, off);
                q3 += __shfl_xor(q3, off);
                q4 += __shfl_xor(q4, off);
                q5 += __shfl_xor(q5, off);
                q6 += __shfl_xor(q6, off);
            }
            if (lane == 0) {
                wsum[wave][0] = q0; wsum[wave][1] = q1; wsum[wave][2] = q2;
                wsum[wave][3] = q3; wsum[wave][4] = q4; wsum[wave][5] = q5;
                wsum[wave][6] = q6;
            }
        }
        __syncthreads();   // sync1

        float inv_rs = 0.f;
        // ---- phase 2: cs, var-choice blend, stage rs/val (t<256) ----
        if (t < 256) {
            float axn = 0, ayn = 0, xny = 0, naa = 0, nxx = 0, nyy = 0, nrs = 0;
#pragma unroll
            for (int w4 = 0; w4 < 4; ++w4) {
                axn += wsum[w4][0]; ayn += wsum[w4][1]; xny += wsum[w4][2];
                naa += wsum[w4][3]; nxx += wsum[w4][4]; nyy += wsum[w4][5];
                nrs += wsum[w4][6];
            }
            const float na = fmaxf(sqrtf(naa), EPS);
            const float nx = fmaxf(sqrtf(nxx), EPS);
            const float ny = fmaxf(sqrtf(nyy), EPS);
            float csarr[3];
            csarr[0] = axn / (na * nx);
            csarr[1] = ayn / (na * ny);
            csarr[2] = xny / (nx * ny);
            inv_rs = 1.0f / fmaxf(sqrtf(nrs), EPS);

            float vc[6];
#pragma unroll
            for (int jj = 0; jj < 6; ++jj) {
                float p = 1.0f;
#pragma unroll
                for (int k = 0; k < 3; ++k) {
                    const float a   = nwv_lds[jj * 3 + k];
                    const float csk = csarr[k];
                    p = p * (a * csk + (1.0f - a) * (1.0f - csk));
                }
                vc[jj] = p;
            }
            const float val = vc[0] * xv + vc[1] * yv
                            + vc[2] * def_lds[0][t] + vc[3] * def_lds[1][t]
                            + vc[4] * def_lds[2][t] + vc[5] * def_lds[3][t];
            rs_lds[t]  = rs;
            val_lds[t] = val;
            float qv = val * val;
#pragma unroll
            for (int off = 32; off >= 1; off >>= 1) qv += __shfl_xor(qv, off);
            if (lane == 0) wsum[wave][7] = qv;
        }
        __syncthreads();   // sync2

        // ---- phase 3: quarter-row dots (all 1024 threads) ----
        // prefetch next step's inputs under the dot compute (t<256)
        float avn = av, xnn = xn, xvn = xv, ynn = yn, yvn = yv;
        if (t < 256) {
            const int sn = (s + 1 < S_LEN) ? s + 1 : s;
            const size_t basen = (size_t)sn * (256 * 256) + (size_t)b * 256 + t;
            avn = av_g[basen]; xnn = xn_g[basen]; xvn = xv_g[basen];
            ynn = yn_g[basen]; yvn = yv_g[basen];
        }
        float dA = 0.f, dB = 0.f, dC = 0.f, dD = 0.f;
        DOTW(W0, 0);   DOTW(W1, 2);   DOTW(W2, 4);   DOTW(W3, 6);
        DOTW(W4, 8);   DOTW(W5, 10);  DOTW(W6, 12);  DOTW(W7, 14);
        DOTW(W8, 16);  DOTW(W9, 18);  DOTW(W10, 20); DOTW(W11, 22);
        DOTW(W12, 24); DOTW(W13, 26); DOTW(W14, 28); DOTW(W15, 30);
        partials[j][c] = (dA + dB) + (dC + dD);
        __syncthreads();   // sync3

        // ---- phase 3b: combine quarters, NAND, redundancy-reduce (t<256) ----
        if (t < 256) {
            const float inv_val = 1.0f / fmaxf(sqrtf(wsum[0][7] + wsum[1][7] +
                                                     wsum[2][7] + wsum[3][7]), EPS);
            const float d0 = partials[0][t] + partials[1][t];
            const float d1 = partials[2][t] + partials[3][t];
            float c0 = d0 * inv_rs  * rowp_lds[0][t];
            float c1 = d1 * inv_val * rowp_lds[1][t];
            c0 = (c0 > 0.f) ? c0 : 0.01f * c0;   // leaky_relu
            c1 = (c1 > 0.f) ? c1 : 0.01f * c1;
            const float nw0 = rowp_lds[2][t];
            const float nw1 = rowp_lds[3][t];
            const float i0 = nw0 * c0 + (1.0f - nw0) * (1.0f - c0);
            const float i1 = nw1 * c1 + (1.0f - nw1) * (1.0f - c1);
            float choice = i0 * i1;
            choice += __shfl_xor(choice, 1);
            choice += __shfl_xor(choice, 2);
            choice += __shfl_xor(choice, 4);
            if ((t & 7) == 0) gw[t >> 3] = choice;
        }
        __syncthreads();   // sync4

        // ---- phase 4: new_rs, store, rotate prefetched inputs (t<256) ----
        if (t < 256) {
            float nrs_new = 0.f;
#pragma unroll
            for (int nc = 0; nc < 32; ++nc) nrs_new += sv_lds[nc][t] * gw[nc];
            rs = nrs_new;
            out[((size_t)b * S_LEN + s) * V_N + t] = rs;
            av = avn; xn = xnn; xv = xvn; yn = ynn; yv = yvn;
        }
        // LDS hazards: every buffer has >=2 barriers between write and reuse.
    }
}

} // namespace

extern "C" void kernel_launch(void* const* d_in, const int* in_sizes, int n_in,
                              void* d_out, int out_size, void* d_ws, size_t ws_size,
                              hipStream_t stream) {
    (void)in_sizes; (void)n_in; (void)d_ws; (void)ws_size; (void)out_size;
    const float* av  = (const float*)d_in[0];
    const float* xn  = (const float*)d_in[1];
    const float* xv  = (const float*)d_in[2];
    const float* yn  = (const float*)d_in[3];
    const float* yv  = (const float*)d_in[4];
    const float* sv  = (const float*)d_in[5];
    const float* sw  = (const float*)d_in[6];
    const float* snw = (const float*)d_in[7];
    const float* def = (const float*)d_in[8];
    const float* vnw = (const float*)d_in[9];
    scan_kernel<<<dim3(256), dim3(1024), 0, stream>>>(
        av, xn, xv, yn, yv, sv, sw, snw, def, vnw, (float*)d_out);
}

// Round 7
// 396.346 us; speedup vs baseline: 5.0170x; 4.9936x over previous
//
#include <hip/hip_runtime.h>
#include <hip/hip_fp16.h>
#include <math.h>

// Round 7: algebraic restructure. rs lives in span(summer_vecs) ->
//   <rs, W0[c]> = sum_k gw[k] * M0T[k][c],  M0T = Sv . W0^T   (32-dot, exact)
//   <val, W1[c]> = vc0*PX[s,b,c] + vc1*PY[s,b,c] + sum_j vc_j*PD[j][c]
// PX/PY are scan-independent GEMMs (x.W1^T, y.W1^T) done once via MFMA f16.
// The scan kernel holds everything in 62KB LDS, no per-thread register arrays
// (rounds 2-6's spill trap is structurally impossible). ws: PXY fp16 33.5MB +
// ~41KB fp32 small arrays = 33.6MB.

namespace {

constexpr int S_LEN = 128;
constexpr int V_N   = 256;
constexpr float EPS = 1e-8f;

typedef _Float16 half8 __attribute__((ext_vector_type(8)));
typedef float    f32x4 __attribute__((ext_vector_type(4)));

__device__ __forceinline__ float sigmoidf_(float x) {
    return 1.0f / (1.0f + expf(-x));
}

// ---------------- K1: weight prep (tiny) ----------------
__global__ void __launch_bounds__(256) prep_kernel(
    const float* __restrict__ sv, const float* __restrict__ sw,
    const float* __restrict__ snw, const float* __restrict__ def,
    float* __restrict__ M0T, float* __restrict__ PD, float* __restrict__ w0s,
    float* __restrict__ invw0, float* __restrict__ invw1,
    float* __restrict__ nws0, float* __restrict__ nws1)
{
    const int b = blockIdx.x, c = threadIdx.x;
    if (b < 32) {                       // M0T[k][c] = <W0[c], Sv[k]>
        float a = 0.f;
        for (int v = 0; v < 256; ++v) a += sw[c * 512 + v] * sv[b * 256 + v];
        M0T[b * 256 + c] = a;
    } else if (b < 36) {                // PD[j][c] = <W1[c], def[j]>
        const int j = b - 32;
        float a = 0.f;
        for (int v = 0; v < 256; ++v) a += sw[c * 512 + 256 + v] * def[j * 256 + v];
        PD[j * 256 + c] = a;
    } else if (b == 36) {               // row sums of W0 (for rs0 = 1e-6*ones)
        float a = 0.f;
        for (int v = 0; v < 256; ++v) a += sw[c * 512 + v];
        w0s[c] = a;
        nws0[c] = sigmoidf_(snw[2 * c]);
        nws1[c] = sigmoidf_(snw[2 * c + 1]);
    } else if (b == 37) {
        float a = 0.f;
        for (int v = 0; v < 256; ++v) { const float w = sw[c * 512 + v]; a += w * w; }
        invw0[c] = 1.0f / fmaxf(sqrtf(a), EPS);
    } else {
        float a = 0.f;
        for (int v = 0; v < 256; ++v) { const float w = sw[c * 512 + 256 + v]; a += w * w; }
        invw1[c] = 1.0f / fmaxf(sqrtf(a), EPS);
    }
}

// ---------------- K2: PXY GEMM via MFMA f16 ----------------
// PXY[m][0..256)  = x[m] . W1^T   (m = s*256+b)
// PXY[m][256..512)= y[m] . W1^T
// wave: 64 rows x 32 cols, K=256; block (4 waves): 256 rows x 32 cols.
// grid 2048 = 8 col-strips x 256 rowblocks (rowblocks 0..127 -> x, 128.. -> y)

#define CVT8(dst, u, w)                                            \
    do {                                                           \
        dst[0] = (_Float16)u.x; dst[1] = (_Float16)u.y;            \
        dst[2] = (_Float16)u.z; dst[3] = (_Float16)u.w;            \
        dst[4] = (_Float16)w.x; dst[5] = (_Float16)w.y;            \
        dst[6] = (_Float16)w.z; dst[7] = (_Float16)w.w;            \
    } while (0)

__global__ void __launch_bounds__(256) pxy_gemm(
    const float* __restrict__ xv, const float* __restrict__ yv,
    const float* __restrict__ sw, __half* __restrict__ pxy)
{
    const int blk      = blockIdx.x;
    const int cstrip   = blk >> 8;           // 0..7
    const int rowblock = blk & 255;          // 0..255
    const int wid  = threadIdx.x >> 6;
    const int lane = threadIdx.x & 63;
    const int l16  = lane & 15;
    const int lhi  = lane >> 4;
    const bool isx = rowblock < 128;
    const float* __restrict__ A = isx ? xv : yv;
    const int row0   = (isx ? rowblock : rowblock - 128) * 256 + wid * 64;
    const int cbase  = cstrip * 32;
    const int colout = isx ? 0 : 256;

    const f32x4 z = {0.f, 0.f, 0.f, 0.f};
    f32x4 acc00 = z, acc01 = z, acc10 = z, acc11 = z;
    f32x4 acc20 = z, acc21 = z, acc30 = z, acc31 = z;

    const float* arow = A  + (size_t)(row0 + l16) * 256;    // + band*16*256
    const float* brow = sw + (size_t)(cbase + l16) * 512 + 256; // + band*16*512

    for (int k0 = 0; k0 < 256; k0 += 32) {
        const int ka = k0 + lhi * 8;
        half8 a0, a1, a2, a3, b0, b1;
        { float4 u = *(const float4*)(arow + ka);
          float4 w = *(const float4*)(arow + ka + 4);            CVT8(a0, u, w); }
        { float4 u = *(const float4*)(arow + 16 * 256 + ka);
          float4 w = *(const float4*)(arow + 16 * 256 + ka + 4); CVT8(a1, u, w); }
        { float4 u = *(const float4*)(arow + 32 * 256 + ka);
          float4 w = *(const float4*)(arow + 32 * 256 + ka + 4); CVT8(a2, u, w); }
        { float4 u = *(const float4*)(arow + 48 * 256 + ka);
          float4 w = *(const float4*)(arow + 48 * 256 + ka + 4); CVT8(a3, u, w); }
        { float4 u = *(const float4*)(brow + ka);
          float4 w = *(const float4*)(brow + ka + 4);            CVT8(b0, u, w); }
        { float4 u = *(const float4*)(brow + 16 * 512 + ka);
          float4 w = *(const float4*)(brow + 16 * 512 + ka + 4); CVT8(b1, u, w); }
        acc00 = __builtin_amdgcn_mfma_f32_16x16x32_f16(a0, b0, acc00, 0, 0, 0);
        acc01 = __builtin_amdgcn_mfma_f32_16x16x32_f16(a0, b1, acc01, 0, 0, 0);
        acc10 = __builtin_amdgcn_mfma_f32_16x16x32_f16(a1, b0, acc10, 0, 0, 0);
        acc11 = __builtin_amdgcn_mfma_f32_16x16x32_f16(a1, b1, acc11, 0, 0, 0);
        acc20 = __builtin_amdgcn_mfma_f32_16x16x32_f16(a2, b0, acc20, 0, 0, 0);
        acc21 = __builtin_amdgcn_mfma_f32_16x16x32_f16(a2, b1, acc21, 0, 0, 0);
        acc30 = __builtin_amdgcn_mfma_f32_16x16x32_f16(a3, b0, acc30, 0, 0, 0);
        acc31 = __builtin_amdgcn_mfma_f32_16x16x32_f16(a3, b1, acc31, 0, 0, 0);
    }

    // C/D layout: col = lane&15, row = (lane>>4)*4 + reg   [guide §3, m89]
    const size_t col = (size_t)colout + cbase + l16;
#pragma unroll
    for (int r = 0; r < 4; ++r) {
        const int rr = lhi * 4 + r;
        pxy[(size_t)(row0 +  0 + rr) * 512 + col]      = __float2half(acc00[r]);
        pxy[(size_t)(row0 +  0 + rr) * 512 + col + 16] = __float2half(acc01[r]);
        pxy[(size_t)(row0 + 16 + rr) * 512 + col]      = __float2half(acc10[r]);
        pxy[(size_t)(row0 + 16 + rr) * 512 + col + 16] = __float2half(acc11[r]);
        pxy[(size_t)(row0 + 32 + rr) * 512 + col]      = __float2half(acc20[r]);
        pxy[(size_t)(row0 + 32 + rr) * 512 + col + 16] = __float2half(acc21[r]);
        pxy[(size_t)(row0 + 48 + rr) * 512 + col]      = __float2half(acc30[r]);
        pxy[(size_t)(row0 + 48 + rr) * 512 + col + 16] = __float2half(acc31[r]);
    }
}

// ---------------- K3: the scan ----------------
__global__ void __launch_bounds__(256) scan_kernel(
    const float* __restrict__ av_g, const float* __restrict__ xn_g,
    const float* __restrict__ xv_g, const float* __restrict__ yn_g,
    const float* __restrict__ yv_g, const float* __restrict__ sv_g,
    const float* __restrict__ def_g, const float* __restrict__ vnw_g,
    const __half* __restrict__ pxy,
    const float* __restrict__ M0T_g, const float* __restrict__ PD_g,
    const float* __restrict__ w0s_g, const float* __restrict__ invw0_g,
    const float* __restrict__ invw1_g, const float* __restrict__ nws0_g,
    const float* __restrict__ nws1_g,
    float* __restrict__ out)
{
    const int b = blockIdx.x;
    const int t = threadIdx.x;
    const int wave = t >> 6, lane = t & 63;

    __shared__ __half M0T_l[32][256];   // 16 KB
    __shared__ float  Sv_l[32][256];    // 32 KB
    __shared__ float  gw_l[2][32];
    __shared__ float  wsum[4][8];
    __shared__ float  nwv_l[18];

    for (int i = t; i < 8192; i += 256) {
        M0T_l[i >> 8][i & 255] = __float2half(M0T_g[i]);
        Sv_l[i >> 8][i & 255]  = sv_g[i];
    }
    if (t < 18) nwv_l[t] = sigmoidf_(vnw_g[t]);

    // step-invariant per-thread scalars (c-role: c == t; v-role: v == t)
    const float pd0 = PD_g[t],       pd1 = PD_g[256 + t];
    const float pd2 = PD_g[512 + t], pd3 = PD_g[768 + t];
    const float df0 = def_g[t],       df1 = def_g[256 + t];
    const float df2 = def_g[512 + t], df3 = def_g[768 + t];
    const float iw0 = invw0_g[t], iw1 = invw1_g[t];
    const float n0  = nws0_g[t],  n1  = nws1_g[t];
    const float w0sum = w0s_g[t];
    __syncthreads();

    float rs = 1e-6f;
    size_t base = (size_t)b * 256 + t;
    float av = av_g[base], xn = xn_g[base], xvv = xv_g[base];
    float yn = yn_g[base], yvv = yv_g[base];
    size_t pb = (size_t)b * 512;
    float px = __half2float(pxy[pb + t]);
    float py = __half2float(pxy[pb + 256 + t]);

    for (int s = 0; s < S_LEN; ++s) {
        // ---- phase A: 7 block reductions ----
        float q0 = av * xn, q1 = av * yn, q2 = xn * yn;
        float q3 = av * av, q4 = xn * xn, q5 = yn * yn, q6 = rs * rs;
#pragma unroll
        for (int off = 32; off >= 1; off >>= 1) {
            q0 += __shfl_xor(q0, off);
            q1 += __shfl_xor(q1, off);
            q2 += __shfl_xor(q2, off);
            q3 += __shfl_xor(q3, off);
            q4 += __shfl_xor(q4, off);
            q5 += __shfl_xor(q5, off);
            q6 += __shfl_xor(q6, off);
        }
        if (lane == 0) {
            wsum[wave][0] = q0; wsum[wave][1] = q1; wsum[wave][2] = q2;
            wsum[wave][3] = q3; wsum[wave][4] = q4; wsum[wave][5] = q5;
            wsum[wave][6] = q6;
        }
        __syncthreads();   // B1
        float axn = 0, ayn = 0, xny = 0, naa = 0, nxx = 0, nyy = 0, nrs = 0;
#pragma unroll
        for (int w = 0; w < 4; ++w) {
            axn += wsum[w][0]; ayn += wsum[w][1]; xny += wsum[w][2];
            naa += wsum[w][3]; nxx += wsum[w][4]; nyy += wsum[w][5];
            nrs += wsum[w][6];
        }
        const float na = fmaxf(sqrtf(naa), EPS);
        const float nx = fmaxf(sqrtf(nxx), EPS);
        const float ny = fmaxf(sqrtf(nyy), EPS);
        float csarr[3];
        csarr[0] = axn / (na * nx);
        csarr[1] = ayn / (na * ny);
        csarr[2] = xny / (nx * ny);
        const float inv_rs = 1.0f / fmaxf(sqrtf(nrs), EPS);

        float vc[6];
#pragma unroll
        for (int jj = 0; jj < 6; ++jj) {
            float p = 1.0f;
#pragma unroll
            for (int k = 0; k < 3; ++k) {
                const float a = nwv_l[jj * 3 + k];
                const float csk = csarr[k];
                p = p * (a * csk + (1.0f - a) * (1.0f - csk));
            }
            vc[jj] = p;
        }

        // ---- phase B: val + |val|^2 reduction ----
        const float val = vc[0] * xvv + vc[1] * yvv
                        + vc[2] * df0 + vc[3] * df1 + vc[4] * df2 + vc[5] * df3;
        float qv = val * val;
#pragma unroll
        for (int off = 32; off >= 1; off >>= 1) qv += __shfl_xor(qv, off);
        if (lane == 0) wsum[wave][7] = qv;
        __syncthreads();   // B2
        const float inv_val = 1.0f / fmaxf(
            sqrtf(wsum[0][7] + wsum[1][7] + wsum[2][7] + wsum[3][7]), EPS);

        // ---- phase C: choices (c = t) ----
        float d0;
        if (s == 0) {
            d0 = 1e-6f * w0sum;
        } else {
            const float* gp = gw_l[(s - 1) & 1];
            d0 = 0.f;
#pragma unroll
            for (int k = 0; k < 32; ++k)
                d0 += __half2float(M0T_l[k][t]) * gp[k];
        }
        const float d1 = vc[0] * px + vc[1] * py
                       + vc[2] * pd0 + vc[3] * pd1 + vc[4] * pd2 + vc[5] * pd3;
        float c0 = d0 * inv_rs  * iw0;
        float c1 = d1 * inv_val * iw1;
        c0 = (c0 > 0.f) ? c0 : 0.01f * c0;   // leaky_relu
        c1 = (c1 > 0.f) ? c1 : 0.01f * c1;
        const float i0 = n0 * c0 + (1.0f - n0) * (1.0f - c0);
        const float i1 = n1 * c1 + (1.0f - n1) * (1.0f - c1);
        float choice = i0 * i1;
        choice += __shfl_xor(choice, 1);
        choice += __shfl_xor(choice, 2);
        choice += __shfl_xor(choice, 4);
        if ((t & 7) == 0) gw_l[s & 1][t >> 3] = choice;

        // prefetch next step's inputs under the barrier
        const int sn = (s + 1 < S_LEN) ? s + 1 : s;
        const size_t basen = (size_t)sn * (256 * 256) + (size_t)b * 256 + t;
        const float avn = av_g[basen], xnn = xn_g[basen], xvn = xv_g[basen];
        const float ynn = yn_g[basen], yvn = yv_g[basen];
        const size_t pbn = ((size_t)sn * 256 + b) * 512;
        const float pxn = __half2float(pxy[pbn + t]);
        const float pyn = __half2float(pxy[pbn + 256 + t]);
        __syncthreads();   // B3

        // ---- phase D: rs_new = Sv^T . gw, store ----
        const float* gc = gw_l[s & 1];
        float rsn = 0.f;
#pragma unroll
        for (int k = 0; k < 32; ++k) rsn += Sv_l[k][t] * gc[k];
        out[((size_t)b * S_LEN + s) * V_N + t] = rsn;
        rs = rsn;
        av = avn; xn = xnn; xvv = xvn; yn = ynn; yvv = yvn;
        px = pxn; py = pyn;
    }
}

} // namespace

extern "C" void kernel_launch(void* const* d_in, const int* in_sizes, int n_in,
                              void* d_out, int out_size, void* d_ws, size_t ws_size,
                              hipStream_t stream) {
    (void)in_sizes; (void)n_in; (void)out_size; (void)ws_size;
    const float* av  = (const float*)d_in[0];
    const float* xnm = (const float*)d_in[1];
    const float* x   = (const float*)d_in[2];
    const float* ynm = (const float*)d_in[3];
    const float* y   = (const float*)d_in[4];
    const float* sv  = (const float*)d_in[5];
    const float* sw  = (const float*)d_in[6];
    const float* snw = (const float*)d_in[7];
    const float* def = (const float*)d_in[8];
    const float* vnw = (const float*)d_in[9];

    // ws layout: [PXY fp16 32768x512 = 33,554,432 B][fp32 small arrays 41,984 B]
    __half* pxy = (__half*)d_ws;
    float* wsf  = (float*)((char*)d_ws + (size_t)32768 * 512 * 2);
    float* M0T   = wsf;          // 8192
    float* PD    = M0T + 8192;   // 1024
    float* w0s   = PD + 1024;    // 256
    float* invw0 = w0s + 256;
    float* invw1 = invw0 + 256;
    float* nws0  = invw1 + 256;
    float* nws1  = nws0 + 256;

    prep_kernel<<<dim3(39), dim3(256), 0, stream>>>(
        sv, sw, snw, def, M0T, PD, w0s, invw0, invw1, nws0, nws1);
    pxy_gemm<<<dim3(2048), dim3(256), 0, stream>>>(x, y, sw, pxy);
    scan_kernel<<<dim3(256), dim3(256), 0, stream>>>(
        av, xnm, x, ynm, y, sv, def, vnw, pxy,
        M0T, PD, w0s, invw0, invw1, nws0, nws1, (float*)d_out);
}

// Round 8
// 371.879 us; speedup vs baseline: 5.3471x; 1.0658x over previous
//
#include <hip/hip_runtime.h>
#include <hip/hip_fp16.h>
#include <math.h>

// Round 8: split the computation by scan-dependence.
//  - i1[s,b,c] (the val-side NAND factor) is scan-INDEPENDENT -> precomputed
//    for all 32768 (s,b) rows in a parallel pass (finish_kernel).
//  - |rs|^2 = gw^T (Sv Sv^T) gw  -> 32x32 Gram G, so the scan never touches
//    V=256 space at all. out = Sv^T gw deferred to expand_kernel (gws 4MB).
//  - scan: ONE WAVE per chain (64 thr, 256 blocks), zero barriers; per step:
//    d0 = M0T^T gw (fp16 LDS tile, 24 b128/lane), gw^T G gw, NAND, 8-way
//    shfl reduce, ds_write gw (wave-in-order LDS; double-buffered).
// Numerics identical to round 7 (fp16 M0T + fp16 pxy; i1 fp32).

namespace {

constexpr float EPS = 1e-8f;

typedef _Float16 half8 __attribute__((ext_vector_type(8)));
typedef float    f32x4 __attribute__((ext_vector_type(4)));

__device__ __forceinline__ float sigmoidf_(float x) {
    return 1.0f / (1.0f + expf(-x));
}

#define RTREE64(p) do { \
    p += __shfl_xor(p, 32); p += __shfl_xor(p, 16); p += __shfl_xor(p, 8); \
    p += __shfl_xor(p, 4);  p += __shfl_xor(p, 2);  p += __shfl_xor(p, 1); } while (0)

// ---------------- K1: prep (coalesced, one barrier) ----------------
// blocks 0..255: per-c row stats + M0T column; blocks 256..287: G rows.
__global__ void __launch_bounds__(256) prep_kernel(
    const float* __restrict__ sv, const float* __restrict__ sw,
    const float* __restrict__ snw, const float* __restrict__ def,
    float* __restrict__ M0T, float* __restrict__ PD, float* __restrict__ G,
    float* __restrict__ w0s, float* __restrict__ iw0, float* __restrict__ iw1,
    float* __restrict__ n0, float* __restrict__ n1)
{
    const int t = threadIdx.x, wave = t >> 6, lane = t & 63;
    __shared__ float wsum[39][4];

    if (blockIdx.x < 256) {
        const int c = blockIdx.x;
        const float w0v = sw[(size_t)c * 512 + t];
        const float w1v = sw[(size_t)c * 512 + 256 + t];
#pragma unroll
        for (int k = 0; k < 32; ++k) {
            float p = w0v * sv[k * 256 + t];
            RTREE64(p);
            if (lane == 0) wsum[k][wave] = p;
        }
#pragma unroll
        for (int j = 0; j < 4; ++j) {
            float p = w1v * def[j * 256 + t];
            RTREE64(p);
            if (lane == 0) wsum[32 + j][wave] = p;
        }
        {
            float p = w0v * w0v; RTREE64(p); if (lane == 0) wsum[36][wave] = p;
            float q = w1v * w1v; RTREE64(q); if (lane == 0) wsum[37][wave] = q;
            float r = w0v;       RTREE64(r); if (lane == 0) wsum[38][wave] = r;
        }
        __syncthreads();
        if (t < 32) {
            M0T[t * 256 + c] = wsum[t][0] + wsum[t][1] + wsum[t][2] + wsum[t][3];
        } else if (t < 36) {
            PD[(t - 32) * 256 + c] =
                wsum[t][0] + wsum[t][1] + wsum[t][2] + wsum[t][3];
        } else if (t == 36) {
            iw0[c] = 1.0f / fmaxf(sqrtf(wsum[36][0] + wsum[36][1] +
                                        wsum[36][2] + wsum[36][3]), EPS);
        } else if (t == 37) {
            iw1[c] = 1.0f / fmaxf(sqrtf(wsum[37][0] + wsum[37][1] +
                                        wsum[37][2] + wsum[37][3]), EPS);
        } else if (t == 38) {
            w0s[c] = wsum[38][0] + wsum[38][1] + wsum[38][2] + wsum[38][3];
        } else if (t == 39) {
            n0[c] = sigmoidf_(snw[2 * c]);
        } else if (t == 40) {
            n1[c] = sigmoidf_(snw[2 * c + 1]);
        }
    } else {
        const int k = blockIdx.x - 256;          // G row
        const float svk = sv[k * 256 + t];
#pragma unroll
        for (int m = 0; m < 32; ++m) {
            float p = svk * sv[m * 256 + t];
            RTREE64(p);
            if (lane == 0) wsum[m][wave] = p;
        }
        __syncthreads();
        if (t < 32)
            G[k * 32 + t] = wsum[t][0] + wsum[t][1] + wsum[t][2] + wsum[t][3];
    }
}

// ---------------- K2: PXY GEMM via MFMA f16 (unchanged from r7) ----------------
#define CVT8(dst, u, w)                                            \
    do {                                                           \
        dst[0] = (_Float16)u.x; dst[1] = (_Float16)u.y;            \
        dst[2] = (_Float16)u.z; dst[3] = (_Float16)u.w;            \
        dst[4] = (_Float16)w.x; dst[5] = (_Float16)w.y;            \
        dst[6] = (_Float16)w.z; dst[7] = (_Float16)w.w;            \
    } while (0)

__global__ void __launch_bounds__(256) pxy_gemm(
    const float* __restrict__ xv, const float* __restrict__ yv,
    const float* __restrict__ sw, __half* __restrict__ pxy)
{
    const int blk      = blockIdx.x;
    const int cstrip   = blk >> 8;
    const int rowblock = blk & 255;
    const int wid  = threadIdx.x >> 6;
    const int lane = threadIdx.x & 63;
    const int l16  = lane & 15;
    const int lhi  = lane >> 4;
    const bool isx = rowblock < 128;
    const float* __restrict__ A = isx ? xv : yv;
    const int row0   = (isx ? rowblock : rowblock - 128) * 256 + wid * 64;
    const int cbase  = cstrip * 32;
    const int colout = isx ? 0 : 256;

    const f32x4 z = {0.f, 0.f, 0.f, 0.f};
    f32x4 acc00 = z, acc01 = z, acc10 = z, acc11 = z;
    f32x4 acc20 = z, acc21 = z, acc30 = z, acc31 = z;

    const float* arow = A  + (size_t)(row0 + l16) * 256;
    const float* brow = sw + (size_t)(cbase + l16) * 512 + 256;

    for (int k0 = 0; k0 < 256; k0 += 32) {
        const int ka = k0 + lhi * 8;
        half8 a0, a1, a2, a3, b0, b1;
        { float4 u = *(const float4*)(arow + ka);
          float4 w = *(const float4*)(arow + ka + 4);            CVT8(a0, u, w); }
        { float4 u = *(const float4*)(arow + 16 * 256 + ka);
          float4 w = *(const float4*)(arow + 16 * 256 + ka + 4); CVT8(a1, u, w); }
        { float4 u = *(const float4*)(arow + 32 * 256 + ka);
          float4 w = *(const float4*)(arow + 32 * 256 + ka + 4); CVT8(a2, u, w); }
        { float4 u = *(const float4*)(arow + 48 * 256 + ka);
          float4 w = *(const float4*)(arow + 48 * 256 + ka + 4); CVT8(a3, u, w); }
        { float4 u = *(const float4*)(brow + ka);
          float4 w = *(const float4*)(brow + ka + 4);            CVT8(b0, u, w); }
        { float4 u = *(const float4*)(brow + 16 * 512 + ka);
          float4 w = *(const float4*)(brow + 16 * 512 + ka + 4); CVT8(b1, u, w); }
        acc00 = __builtin_amdgcn_mfma_f32_16x16x32_f16(a0, b0, acc00, 0, 0, 0);
        acc01 = __builtin_amdgcn_mfma_f32_16x16x32_f16(a0, b1, acc01, 0, 0, 0);
        acc10 = __builtin_amdgcn_mfma_f32_16x16x32_f16(a1, b0, acc10, 0, 0, 0);
        acc11 = __builtin_amdgcn_mfma_f32_16x16x32_f16(a1, b1, acc11, 0, 0, 0);
        acc20 = __builtin_amdgcn_mfma_f32_16x16x32_f16(a2, b0, acc20, 0, 0, 0);
        acc21 = __builtin_amdgcn_mfma_f32_16x16x32_f16(a2, b1, acc21, 0, 0, 0);
        acc30 = __builtin_amdgcn_mfma_f32_16x16x32_f16(a3, b0, acc30, 0, 0, 0);
        acc31 = __builtin_amdgcn_mfma_f32_16x16x32_f16(a3, b1, acc31, 0, 0, 0);
    }

    const size_t col = (size_t)colout + cbase + l16;
#pragma unroll
    for (int r = 0; r < 4; ++r) {
        const int rr = lhi * 4 + r;
        pxy[(size_t)(row0 +  0 + rr) * 512 + col]      = __float2half(acc00[r]);
        pxy[(size_t)(row0 +  0 + rr) * 512 + col + 16] = __float2half(acc01[r]);
        pxy[(size_t)(row0 + 16 + rr) * 512 + col]      = __float2half(acc10[r]);
        pxy[(size_t)(row0 + 16 + rr) * 512 + col + 16] = __float2half(acc11[r]);
        pxy[(size_t)(row0 + 32 + rr) * 512 + col]      = __float2half(acc20[r]);
        pxy[(size_t)(row0 + 32 + rr) * 512 + col + 16] = __float2half(acc21[r]);
        pxy[(size_t)(row0 + 48 + rr) * 512 + col]      = __float2half(acc30[r]);
        pxy[(size_t)(row0 + 48 + rr) * 512 + col + 16] = __float2half(acc31[r]);
    }
}

// ---------------- K3: finish — precompute i1[s,b,c] ----------------
__global__ void __launch_bounds__(256) finish_kernel(
    const float* __restrict__ av_g, const float* __restrict__ xn_g,
    const float* __restrict__ yn_g, const float* __restrict__ xv_g,
    const float* __restrict__ yv_g, const float* __restrict__ def_g,
    const float* __restrict__ vnw_g, const float* __restrict__ PD_g,
    const float* __restrict__ iw1_g, const float* __restrict__ n1_g,
    const __half* __restrict__ pxy, float* __restrict__ i1_g)
{
    const int m = blockIdx.x;                 // m = s*256 + b
    const int t = threadIdx.x, wave = t >> 6, lane = t & 63;
    __shared__ float wsum[8][4];
    __shared__ float nwv_l[18];
    if (t < 18) nwv_l[t] = sigmoidf_(vnw_g[t]);

    const size_t base = (size_t)m * 256 + t;
    const float av = av_g[base], xn = xn_g[base], yn = yn_g[base];
    const float xv = xv_g[base], yv = yv_g[base];

    {
        float p0 = av * xn, p1 = av * yn, p2 = xn * yn;
        float p3 = av * av, p4 = xn * xn, p5 = yn * yn;
        RTREE64(p0); RTREE64(p1); RTREE64(p2);
        RTREE64(p3); RTREE64(p4); RTREE64(p5);
        if (lane == 0) {
            wsum[0][wave] = p0; wsum[1][wave] = p1; wsum[2][wave] = p2;
            wsum[3][wave] = p3; wsum[4][wave] = p4; wsum[5][wave] = p5;
        }
    }
    __syncthreads();
    const float axn = wsum[0][0] + wsum[0][1] + wsum[0][2] + wsum[0][3];
    const float ayn = wsum[1][0] + wsum[1][1] + wsum[1][2] + wsum[1][3];
    const float xny = wsum[2][0] + wsum[2][1] + wsum[2][2] + wsum[2][3];
    const float naa = wsum[3][0] + wsum[3][1] + wsum[3][2] + wsum[3][3];
    const float nxx = wsum[4][0] + wsum[4][1] + wsum[4][2] + wsum[4][3];
    const float nyy = wsum[5][0] + wsum[5][1] + wsum[5][2] + wsum[5][3];
    const float na = fmaxf(sqrtf(naa), EPS);
    const float nx = fmaxf(sqrtf(nxx), EPS);
    const float ny = fmaxf(sqrtf(nyy), EPS);
    float csarr[3];
    csarr[0] = axn / (na * nx);
    csarr[1] = ayn / (na * ny);
    csarr[2] = xny / (nx * ny);

    float vc[6];
#pragma unroll
    for (int jj = 0; jj < 6; ++jj) {
        float p = 1.0f;
#pragma unroll
        for (int k = 0; k < 3; ++k) {
            const float a = nwv_l[jj * 3 + k];
            const float csk = csarr[k];
            p = p * (a * csk + (1.0f - a) * (1.0f - csk));
        }
        vc[jj] = p;
    }

    const float val = vc[0] * xv + vc[1] * yv
                    + vc[2] * def_g[t]       + vc[3] * def_g[256 + t]
                    + vc[4] * def_g[512 + t] + vc[5] * def_g[768 + t];
    float qv = val * val;
    RTREE64(qv);
    if (lane == 0) wsum[7][wave] = qv;
    __syncthreads();
    const float inv_val = 1.0f / fmaxf(
        sqrtf(wsum[7][0] + wsum[7][1] + wsum[7][2] + wsum[7][3]), EPS);

    const float px = __half2float(pxy[(size_t)m * 512 + t]);
    const float py = __half2float(pxy[(size_t)m * 512 + 256 + t]);
    const float d1 = vc[0] * px + vc[1] * py
                   + vc[2] * PD_g[t]       + vc[3] * PD_g[256 + t]
                   + vc[4] * PD_g[512 + t] + vc[5] * PD_g[768 + t];
    float c1 = d1 * inv_val * iw1_g[t];
    c1 = (c1 > 0.f) ? c1 : 0.01f * c1;      // leaky_relu
    const float nn = n1_g[t];
    i1_g[(size_t)m * 256 + t] = nn * c1 + (1.0f - nn) * (1.0f - c1);
}

// ---------------- K4: the scan — one wave per chain, no barriers ----------------
__global__ void __launch_bounds__(64) scan_kernel(
    const float* __restrict__ i1_g, const float* __restrict__ M0T_g,
    const float* __restrict__ G_g, const float* __restrict__ w0s_g,
    const float* __restrict__ iw0_g, const float* __restrict__ n0_g,
    float* __restrict__ gws_g)
{
    const int b = blockIdx.x;
    const int L = threadIdx.x;              // 0..63

    __shared__ __align__(16) __half M0Th[256 * 40];    // [c][k], rows padded to 40
    __shared__ __align__(16) float  G_l[32 * 36];      // [k][m], rows padded to 36
    __shared__ __align__(16) float  gw_l[2][32];

    for (int i = L; i < 8192; i += 64) {
        const int k = i >> 8, c = i & 255;
        M0Th[c * 40 + k] = __float2half(M0T_g[i]);
    }
    for (int i = L; i < 1024; i += 64) {
        const int k = i >> 5, mm = i & 31;
        G_l[k * 36 + mm] = G_g[i];
    }
    __syncthreads();

    const int c0_ = L, c1_ = L + 64, c2_ = L + 128, c3_ = L + 192;
    const float iwq0 = iw0_g[c0_], iwq1 = iw0_g[c1_];
    const float iwq2 = iw0_g[c2_], iwq3 = iw0_g[c3_];
    const float n0q0 = n0_g[c0_], n0q1 = n0_g[c1_];
    const float n0q2 = n0_g[c2_], n0q3 = n0_g[c3_];
    const float di0 = 1e-6f * w0s_g[c0_], di1 = 1e-6f * w0s_g[c1_];
    const float di2 = 1e-6f * w0s_g[c2_], di3 = 1e-6f * w0s_g[c3_];
    const int col = L & 31;

    size_t rowb = (size_t)b * 256;          // i1 row base for s=0
    float i1a0 = i1_g[rowb + c0_], i1a1 = i1_g[rowb + c1_];
    float i1a2 = i1_g[rowb + c2_], i1a3 = i1_g[rowb + c3_];

    for (int s = 0; s < 128; ++s) {
        // prefetch i1 for s+1 (issued early, consumed next iteration)
        const int sn = (s + 1 < 128) ? s + 1 : s;
        const size_t rowbn = ((size_t)sn * 256 + b) * 256;
        const float i1b0 = i1_g[rowbn + c0_], i1b1 = i1_g[rowbn + c1_];
        const float i1b2 = i1_g[rowbn + c2_], i1b3 = i1_g[rowbn + c3_];

        float d0 = 0.f, d1 = 0.f, d2 = 0.f, d3 = 0.f, rs2;
        if (s == 0) {
            d0 = di0; d1 = di1; d2 = di2; d3 = di3;
            rs2 = 2.56e-10f;                 // |1e-6 * ones(256)|^2
        } else {
            const float* gbuf = gw_l[s & 1];
            float ginner = 0.f;
#pragma unroll
            for (int j = 0; j < 4; ++j) {
                const float4 ga = *(const float4*)(gbuf + 8 * j);
                const float4 gb = *(const float4*)(gbuf + 8 * j + 4);
                // G column walk (conflict-free: bank == col)
                ginner += G_l[(8 * j + 0) * 36 + col] * ga.x
                        + G_l[(8 * j + 1) * 36 + col] * ga.y
                        + G_l[(8 * j + 2) * 36 + col] * ga.z
                        + G_l[(8 * j + 3) * 36 + col] * ga.w
                        + G_l[(8 * j + 4) * 36 + col] * gb.x
                        + G_l[(8 * j + 5) * 36 + col] * gb.y
                        + G_l[(8 * j + 6) * 36 + col] * gb.z
                        + G_l[(8 * j + 7) * 36 + col] * gb.w;
#define DOTQ(ACC, CQ)                                                      \
                do {                                                       \
                    const uint4 mw = *(const uint4*)(&M0Th[(CQ) * 40 + 8 * j]); \
                    union { unsigned u; __half2 h; } u0, u1, u2, u3;       \
                    u0.u = mw.x; u1.u = mw.y; u2.u = mw.z; u3.u = mw.w;    \
                    const float2 f0 = __half22float2(u0.h);                \
                    const float2 f1 = __half22float2(u1.h);                \
                    const float2 f2 = __half22float2(u2.h);                \
                    const float2 f3 = __half22float2(u3.h);                \
                    ACC += f0.x * ga.x + f0.y * ga.y + f1.x * ga.z         \
                         + f1.y * ga.w + f2.x * gb.x + f2.y * gb.y         \
                         + f3.x * gb.z + f3.y * gb.w;                      \
                } while (0)
                DOTQ(d0, c0_); DOTQ(d1, c1_); DOTQ(d2, c2_); DOTQ(d3, c3_);
#undef DOTQ
            }
            float rp = ginner * gbuf[col];
            rp += __shfl_xor(rp, 1);  rp += __shfl_xor(rp, 2);
            rp += __shfl_xor(rp, 4);  rp += __shfl_xor(rp, 8);
            rp += __shfl_xor(rp, 16);
            rs2 = rp;
        }
        const float inv_rs = 1.0f / fmaxf(sqrtf(rs2), EPS);

        float* gnext = gw_l[(s + 1) & 1];
        const size_t grow = ((size_t)s * 256 + b) << 5;
#define CHQ(Q, DQ, IW, N0, I1A)                                            \
        do {                                                               \
            float cc = (DQ) * inv_rs * (IW);                               \
            cc = (cc > 0.f) ? cc : 0.01f * cc;                             \
            const float i0v = (N0) * cc + (1.0f - (N0)) * (1.0f - cc);     \
            float ch = i0v * (I1A);                                        \
            ch += __shfl_xor(ch, 1);                                       \
            ch += __shfl_xor(ch, 2);                                       \
            ch += __shfl_xor(ch, 4);                                       \
            if ((L & 7) == 0) {                                            \
                const int nc = 8 * (Q) + (L >> 3);                         \
                gnext[nc] = ch;                                            \
                gws_g[grow + nc] = ch;                                     \
            }                                                              \
        } while (0)
        CHQ(0, d0, iwq0, n0q0, i1a0);
        CHQ(1, d1, iwq1, n0q1, i1a1);
        CHQ(2, d2, iwq2, n0q2, i1a2);
        CHQ(3, d3, iwq3, n0q3, i1a3);
#undef CHQ
        i1a0 = i1b0; i1a1 = i1b1; i1a2 = i1b2; i1a3 = i1b3;
    }
}

// ---------------- K5: expand out[b,s,v] = Sv^T gw ----------------
__global__ void __launch_bounds__(256) expand_kernel(
    const float* __restrict__ gws_g, const float* __restrict__ sv_g,
    float* __restrict__ out)
{
    const int t = threadIdx.x;
    const int m0 = blockIdx.x * 32;
    __shared__ __align__(16) float SvT[256 * 36];   // [v][k] padded
    __shared__ __align__(16) float gwl[32 * 32];    // [row][k]

    for (int i = t; i < 8192; i += 256) {
        const int k = i >> 8, v = i & 255;
        SvT[v * 36 + k] = sv_g[i];
    }
    for (int i = t; i < 1024; i += 256)
        gwl[i] = gws_g[(size_t)m0 * 32 + i];
    __syncthreads();

#pragma unroll 4
    for (int r = 0; r < 32; ++r) {
        float acc = 0.f;
#pragma unroll
        for (int j = 0; j < 8; ++j) {
            const float4 g  = *(const float4*)(gwl + r * 32 + 4 * j);
            const float4 sv4 = *(const float4*)(SvT + t * 36 + 4 * j);
            acc += g.x * sv4.x + g.y * sv4.y + g.z * sv4.z + g.w * sv4.w;
        }
        const int m = m0 + r;
        const int s = m >> 8, bb = m & 255;
        out[((size_t)bb * 128 + s) * 256 + t] = acc;
    }
}

} // namespace

extern "C" void kernel_launch(void* const* d_in, const int* in_sizes, int n_in,
                              void* d_out, int out_size, void* d_ws, size_t ws_size,
                              hipStream_t stream) {
    (void)in_sizes; (void)n_in; (void)out_size; (void)ws_size;
    const float* av  = (const float*)d_in[0];
    const float* xnm = (const float*)d_in[1];
    const float* x   = (const float*)d_in[2];
    const float* ynm = (const float*)d_in[3];
    const float* y   = (const float*)d_in[4];
    const float* sv  = (const float*)d_in[5];
    const float* sw  = (const float*)d_in[6];
    const float* snw = (const float*)d_in[7];
    const float* def = (const float*)d_in[8];
    const float* vnw = (const float*)d_in[9];

    // ws layout: pxy fp16 33.55MB | i1 fp32 33.55MB | gws fp32 4.19MB | smalls
    __half* pxy = (__half*)d_ws;
    float*  i1  = (float*)((char*)d_ws + (size_t)33554432);
    float*  gws = i1 + 8388608;
    float*  sm  = gws + 1048576;
    float* M0T = sm;            // 8192
    float* PD  = M0T + 8192;    // 1024
    float* G   = PD + 1024;     // 1024
    float* w0s = G + 1024;      // 256
    float* iw0 = w0s + 256;
    float* iw1 = iw0 + 256;
    float* n0  = iw1 + 256;
    float* n1  = n0 + 256;

    prep_kernel<<<dim3(288), dim3(256), 0, stream>>>(
        sv, sw, snw, def, M0T, PD, G, w0s, iw0, iw1, n0, n1);
    pxy_gemm<<<dim3(2048), dim3(256), 0, stream>>>(x, y, sw, pxy);
    finish_kernel<<<dim3(32768), dim3(256), 0, stream>>>(
        av, xnm, ynm, x, y, def, vnw, PD, iw1, n1, pxy, i1);
    scan_kernel<<<dim3(256), dim3(64), 0, stream>>>(
        i1, M0T, G, w0s, iw0, n0, gws);
    expand_kernel<<<dim3(1024), dim3(256), 0, stream>>>(gws, sv, (float*)d_out);
}

// Round 9
// 332.653 us; speedup vs baseline: 5.9776x; 1.1179x over previous
//
#include <hip/hip_runtime.h>
#include <hip/hip_fp16.h>
#include <math.h>

// Round 9: scan de-latencying. Round 8 scan = 168us, 3150cy/step, dominated by
// 17 dependent __shfl_xor (ds_bpermute ~100cy each, zero TLP at 1 wave/CU) +
// 196K bank conflicts. Changes (algorithm identical):
//  - lane l owns c=4l..4l+3 (one redundancy half-group): 8-way reduce = 3 local
//    adds + 1 DPP quad-perm add (was 12 bpermutes).
//  - rs2 = gw^T G gw distributed over 64 lanes (col=l&31, k-half=l>>5):
//    4 DPP row_ror adds + 4 readlane (was 5 bpermutes); result SGPR-uniform.
//  - M0T in LDS permuted [q][j][lane] -> every ds_read_b128 conflict-free;
//    prep emits fp16 c-major M0T so the loader is a straight b128 copy.
//  - i1/iw0/n0/w0s as per-lane float4; i1 prefetched a step ahead.

namespace {

constexpr float EPS = 1e-8f;

typedef _Float16 half8 __attribute__((ext_vector_type(8)));
typedef float    f32x4 __attribute__((ext_vector_type(4)));

__device__ __forceinline__ float sigmoidf_(float x) {
    return 1.0f / (1.0f + expf(-x));
}

__device__ __forceinline__ float2 up2(unsigned u) {
    union { unsigned u; __half2 h2; } cvt;
    cvt.u = u;
    return __half22float2(cvt.h2);
}

#define RTREE64(p) do { \
    p += __shfl_xor(p, 32); p += __shfl_xor(p, 16); p += __shfl_xor(p, 8); \
    p += __shfl_xor(p, 4);  p += __shfl_xor(p, 2);  p += __shfl_xor(p, 1); } while (0)

// DPP helpers (ctrl must be ICE). row_ror:n = 0x120+n, quad_perm xor1 = 0xB1.
#define DPP_ADD(x, CTRL) \
    ((x) + __int_as_float(__builtin_amdgcn_mov_dpp( \
        __float_as_int(x), (CTRL), 0xF, 0xF, true)))
#define RDLANE(x, L) \
    __int_as_float(__builtin_amdgcn_readlane(__float_as_int(x), (L)))

// ---------------- K1: prep ----------------
// blocks 0..255: per-c row stats + M0T column (fp32 k-major AND fp16 c-major);
// blocks 256..287: G rows.
__global__ void __launch_bounds__(256) prep_kernel(
    const float* __restrict__ sv, const float* __restrict__ sw,
    const float* __restrict__ snw, const float* __restrict__ def,
    float* __restrict__ M0T, __half* __restrict__ M0Th,
    float* __restrict__ PD, float* __restrict__ G,
    float* __restrict__ w0s, float* __restrict__ iw0, float* __restrict__ iw1,
    float* __restrict__ n0, float* __restrict__ n1)
{
    const int t = threadIdx.x, wave = t >> 6, lane = t & 63;
    __shared__ float wsum[39][4];

    if (blockIdx.x < 256) {
        const int c = blockIdx.x;
        const float w0v = sw[(size_t)c * 512 + t];
        const float w1v = sw[(size_t)c * 512 + 256 + t];
#pragma unroll
        for (int k = 0; k < 32; ++k) {
            float p = w0v * sv[k * 256 + t];
            RTREE64(p);
            if (lane == 0) wsum[k][wave] = p;
        }
#pragma unroll
        for (int j = 0; j < 4; ++j) {
            float p = w1v * def[j * 256 + t];
            RTREE64(p);
            if (lane == 0) wsum[32 + j][wave] = p;
        }
        {
            float p = w0v * w0v; RTREE64(p); if (lane == 0) wsum[36][wave] = p;
            float q = w1v * w1v; RTREE64(q); if (lane == 0) wsum[37][wave] = q;
            float r = w0v;       RTREE64(r); if (lane == 0) wsum[38][wave] = r;
        }
        __syncthreads();
        if (t < 32) {
            const float v = wsum[t][0] + wsum[t][1] + wsum[t][2] + wsum[t][3];
            M0T[t * 256 + c] = v;
            M0Th[c * 32 + t] = __float2half(v);
        } else if (t < 36) {
            PD[(t - 32) * 256 + c] =
                wsum[t][0] + wsum[t][1] + wsum[t][2] + wsum[t][3];
        } else if (t == 36) {
            iw0[c] = 1.0f / fmaxf(sqrtf(wsum[36][0] + wsum[36][1] +
                                        wsum[36][2] + wsum[36][3]), EPS);
        } else if (t == 37) {
            iw1[c] = 1.0f / fmaxf(sqrtf(wsum[37][0] + wsum[37][1] +
                                        wsum[37][2] + wsum[37][3]), EPS);
        } else if (t == 38) {
            w0s[c] = wsum[38][0] + wsum[38][1] + wsum[38][2] + wsum[38][3];
        } else if (t == 39) {
            n0[c] = sigmoidf_(snw[2 * c]);
        } else if (t == 40) {
            n1[c] = sigmoidf_(snw[2 * c + 1]);
        }
    } else {
        const int k = blockIdx.x - 256;
        const float svk = sv[k * 256 + t];
#pragma unroll
        for (int m = 0; m < 32; ++m) {
            float p = svk * sv[m * 256 + t];
            RTREE64(p);
            if (lane == 0) wsum[m][wave] = p;
        }
        __syncthreads();
        if (t < 32)
            G[k * 32 + t] = wsum[t][0] + wsum[t][1] + wsum[t][2] + wsum[t][3];
    }
}

// ---------------- K2: PXY GEMM via MFMA f16 (unchanged) ----------------
#define CVT8(dst, u, w)                                            \
    do {                                                           \
        dst[0] = (_Float16)u.x; dst[1] = (_Float16)u.y;            \
        dst[2] = (_Float16)u.z; dst[3] = (_Float16)u.w;            \
        dst[4] = (_Float16)w.x; dst[5] = (_Float16)w.y;            \
        dst[6] = (_Float16)w.z; dst[7] = (_Float16)w.w;            \
    } while (0)

__global__ void __launch_bounds__(256) pxy_gemm(
    const float* __restrict__ xv, const float* __restrict__ yv,
    const float* __restrict__ sw, __half* __restrict__ pxy)
{
    const int blk      = blockIdx.x;
    const int cstrip   = blk >> 8;
    const int rowblock = blk & 255;
    const int wid  = threadIdx.x >> 6;
    const int lane = threadIdx.x & 63;
    const int l16  = lane & 15;
    const int lhi  = lane >> 4;
    const bool isx = rowblock < 128;
    const float* __restrict__ A = isx ? xv : yv;
    const int row0   = (isx ? rowblock : rowblock - 128) * 256 + wid * 64;
    const int cbase  = cstrip * 32;
    const int colout = isx ? 0 : 256;

    const f32x4 z = {0.f, 0.f, 0.f, 0.f};
    f32x4 acc00 = z, acc01 = z, acc10 = z, acc11 = z;
    f32x4 acc20 = z, acc21 = z, acc30 = z, acc31 = z;

    const float* arow = A  + (size_t)(row0 + l16) * 256;
    const float* brow = sw + (size_t)(cbase + l16) * 512 + 256;

    for (int k0 = 0; k0 < 256; k0 += 32) {
        const int ka = k0 + lhi * 8;
        half8 a0, a1, a2, a3, b0, b1;
        { float4 u = *(const float4*)(arow + ka);
          float4 w = *(const float4*)(arow + ka + 4);            CVT8(a0, u, w); }
        { float4 u = *(const float4*)(arow + 16 * 256 + ka);
          float4 w = *(const float4*)(arow + 16 * 256 + ka + 4); CVT8(a1, u, w); }
        { float4 u = *(const float4*)(arow + 32 * 256 + ka);
          float4 w = *(const float4*)(arow + 32 * 256 + ka + 4); CVT8(a2, u, w); }
        { float4 u = *(const float4*)(arow + 48 * 256 + ka);
          float4 w = *(const float4*)(arow + 48 * 256 + ka + 4); CVT8(a3, u, w); }
        { float4 u = *(const float4*)(brow + ka);
          float4 w = *(const float4*)(brow + ka + 4);            CVT8(b0, u, w); }
        { float4 u = *(const float4*)(brow + 16 * 512 + ka);
          float4 w = *(const float4*)(brow + 16 * 512 + ka + 4); CVT8(b1, u, w); }
        acc00 = __builtin_amdgcn_mfma_f32_16x16x32_f16(a0, b0, acc00, 0, 0, 0);
        acc01 = __builtin_amdgcn_mfma_f32_16x16x32_f16(a0, b1, acc01, 0, 0, 0);
        acc10 = __builtin_amdgcn_mfma_f32_16x16x32_f16(a1, b0, acc10, 0, 0, 0);
        acc11 = __builtin_amdgcn_mfma_f32_16x16x32_f16(a1, b1, acc11, 0, 0, 0);
        acc20 = __builtin_amdgcn_mfma_f32_16x16x32_f16(a2, b0, acc20, 0, 0, 0);
        acc21 = __builtin_amdgcn_mfma_f32_16x16x32_f16(a2, b1, acc21, 0, 0, 0);
        acc30 = __builtin_amdgcn_mfma_f32_16x16x32_f16(a3, b0, acc30, 0, 0, 0);
        acc31 = __builtin_amdgcn_mfma_f32_16x16x32_f16(a3, b1, acc31, 0, 0, 0);
    }

    const size_t col = (size_t)colout + cbase + l16;
#pragma unroll
    for (int r = 0; r < 4; ++r) {
        const int rr = lhi * 4 + r;
        pxy[(size_t)(row0 +  0 + rr) * 512 + col]      = __float2half(acc00[r]);
        pxy[(size_t)(row0 +  0 + rr) * 512 + col + 16] = __float2half(acc01[r]);
        pxy[(size_t)(row0 + 16 + rr) * 512 + col]      = __float2half(acc10[r]);
        pxy[(size_t)(row0 + 16 + rr) * 512 + col + 16] = __float2half(acc11[r]);
        pxy[(size_t)(row0 + 32 + rr) * 512 + col]      = __float2half(acc20[r]);
        pxy[(size_t)(row0 + 32 + rr) * 512 + col + 16] = __float2half(acc21[r]);
        pxy[(size_t)(row0 + 48 + rr) * 512 + col]      = __float2half(acc30[r]);
        pxy[(size_t)(row0 + 48 + rr) * 512 + col + 16] = __float2half(acc31[r]);
    }
}

// ---------------- K3: finish — precompute i1[s,b,c] (unchanged) ----------------
__global__ void __launch_bounds__(256) finish_kernel(
    const float* __restrict__ av_g, const float* __restrict__ xn_g,
    const float* __restrict__ yn_g, const float* __restrict__ xv_g,
    const float* __restrict__ yv_g, const float* __restrict__ def_g,
    const float* __restrict__ vnw_g, const float* __restrict__ PD_g,
    const float* __restrict__ iw1_g, const float* __restrict__ n1_g,
    const __half* __restrict__ pxy, float* __restrict__ i1_g)
{
    const int m = blockIdx.x;
    const int t = threadIdx.x, wave = t >> 6, lane = t & 63;
    __shared__ float wsum[8][4];
    __shared__ float nwv_l[18];
    if (t < 18) nwv_l[t] = sigmoidf_(vnw_g[t]);

    const size_t base = (size_t)m * 256 + t;
    const float av = av_g[base], xn = xn_g[base], yn = yn_g[base];
    const float xv = xv_g[base], yv = yv_g[base];

    {
        float p0 = av * xn, p1 = av * yn, p2 = xn * yn;
        float p3 = av * av, p4 = xn * xn, p5 = yn * yn;
        RTREE64(p0); RTREE64(p1); RTREE64(p2);
        RTREE64(p3); RTREE64(p4); RTREE64(p5);
        if (lane == 0) {
            wsum[0][wave] = p0; wsum[1][wave] = p1; wsum[2][wave] = p2;
            wsum[3][wave] = p3; wsum[4][wave] = p4; wsum[5][wave] = p5;
        }
    }
    __syncthreads();
    const float axn = wsum[0][0] + wsum[0][1] + wsum[0][2] + wsum[0][3];
    const float ayn = wsum[1][0] + wsum[1][1] + wsum[1][2] + wsum[1][3];
    const float xny = wsum[2][0] + wsum[2][1] + wsum[2][2] + wsum[2][3];
    const float naa = wsum[3][0] + wsum[3][1] + wsum[3][2] + wsum[3][3];
    const float nxx = wsum[4][0] + wsum[4][1] + wsum[4][2] + wsum[4][3];
    const float nyy = wsum[5][0] + wsum[5][1] + wsum[5][2] + wsum[5][3];
    const float na = fmaxf(sqrtf(naa), EPS);
    const float nx = fmaxf(sqrtf(nxx), EPS);
    const float ny = fmaxf(sqrtf(nyy), EPS);
    float csarr[3];
    csarr[0] = axn / (na * nx);
    csarr[1] = ayn / (na * ny);
    csarr[2] = xny / (nx * ny);

    float vc[6];
#pragma unroll
    for (int jj = 0; jj < 6; ++jj) {
        float p = 1.0f;
#pragma unroll
        for (int k = 0; k < 3; ++k) {
            const float a = nwv_l[jj * 3 + k];
            const float csk = csarr[k];
            p = p * (a * csk + (1.0f - a) * (1.0f - csk));
        }
        vc[jj] = p;
    }

    const float val = vc[0] * xv + vc[1] * yv
                    + vc[2] * def_g[t]       + vc[3] * def_g[256 + t]
                    + vc[4] * def_g[512 + t] + vc[5] * def_g[768 + t];
    float qv = val * val;
    RTREE64(qv);
    if (lane == 0) wsum[7][wave] = qv;
    __syncthreads();
    const float inv_val = 1.0f / fmaxf(
        sqrtf(wsum[7][0] + wsum[7][1] + wsum[7][2] + wsum[7][3]), EPS);

    const float px = __half2float(pxy[(size_t)m * 512 + t]);
    const float py = __half2float(pxy[(size_t)m * 512 + 256 + t]);
    const float d1 = vc[0] * px + vc[1] * py
                   + vc[2] * PD_g[t]       + vc[3] * PD_g[256 + t]
                   + vc[4] * PD_g[512 + t] + vc[5] * PD_g[768 + t];
    float c1 = d1 * inv_val * iw1_g[t];
    c1 = (c1 > 0.f) ? c1 : 0.01f * c1;
    const float nn = n1_g[t];
    i1_g[(size_t)m * 256 + t] = nn * c1 + (1.0f - nn) * (1.0f - c1);
}

// ---------------- K4: the scan — DPP reduces, conflict-free LDS ----------------
__global__ void __launch_bounds__(64)
__attribute__((amdgpu_waves_per_eu(1)))
scan_kernel(
    const float* __restrict__ i1_g, const __half* __restrict__ M0Th_g,
    const float* __restrict__ G_g, const float* __restrict__ w0s_g,
    const float* __restrict__ iw0_g, const float* __restrict__ n0_g,
    float* __restrict__ gws_g)
{
    const int b = blockIdx.x;
    const int L = threadIdx.x;              // 0..63; owns c = 4L..4L+3

    __shared__ __align__(16) __half M0Tp[8192];   // [q][j][lane][8] 16KB
    __shared__ __align__(16) float  G_l[1024];    // [k][m] 4KB
    __shared__ __align__(16) float  gw_l[2][32];

    // M0Tp[(q*4+j)*64 + L] (16B entry) = M0T[k=8j..8j+7][c=4L+q]
    for (int e = L; e < 1024; e += 64) {
        const int q = e >> 8, j = (e >> 6) & 3;   // e&63 == L
        const int c = 4 * L + q;
        const uint4 v = *(const uint4*)(M0Th_g + c * 32 + 8 * j);
        *(uint4*)(&M0Tp[(size_t)e * 8]) = v;
    }
    for (int i = L; i < 1024; i += 64) G_l[i] = G_g[i];

    const float4 w0s4 = *(const float4*)(w0s_g + 4 * L);
    const float4 iw4  = *(const float4*)(iw0_g + 4 * L);
    const float4 n04  = *(const float4*)(n0_g + 4 * L);
    const float4 di = {1e-6f * w0s4.x, 1e-6f * w0s4.y,
                       1e-6f * w0s4.z, 1e-6f * w0s4.w};
    const float4 An = {2.f * n04.x - 1.f, 2.f * n04.y - 1.f,
                       2.f * n04.z - 1.f, 2.f * n04.w - 1.f};
    const float4 Bn = {1.f - n04.x, 1.f - n04.y, 1.f - n04.z, 1.f - n04.w};
    const int col   = L & 31;
    const bool hi   = (L >= 32);
    const int gbase = col + (hi ? 512 : 0);
    __syncthreads();

    float4 i1c = *(const float4*)(i1_g + (size_t)b * 256 + 4 * L);

    for (int s = 0; s < 128; ++s) {
        const int sn = (s + 1 < 128) ? s + 1 : s;
        const float4 i1n = *(const float4*)(
            i1_g + ((size_t)sn * 256 + b) * 256 + 4 * L);

        float d0, d1, d2, d3, rs2;
        if (s == 0) {
            d0 = di.x; d1 = di.y; d2 = di.z; d3 = di.w;
            rs2 = 2.56e-10f;                 // |1e-6 * ones(256)|^2
        } else {
            const float* gp = gw_l[(s - 1) & 1];
            const float4 g0 = *(const float4*)(gp +  0);
            const float4 g1 = *(const float4*)(gp +  4);
            const float4 g2 = *(const float4*)(gp +  8);
            const float4 g3 = *(const float4*)(gp + 12);
            const float4 g4 = *(const float4*)(gp + 16);
            const float4 g5 = *(const float4*)(gp + 20);
            const float4 g6 = *(const float4*)(gp + 24);
            const float4 g7 = *(const float4*)(gp + 28);
            const float gwcol = gp[col];

            d0 = d1 = d2 = d3 = 0.f;
#define D8(ACC, MW, GA, GB)                                        \
            do {                                                   \
                float2 f;                                          \
                f = up2((MW).x); ACC += f.x * GA.x + f.y * GA.y;   \
                f = up2((MW).y); ACC += f.x * GA.z + f.y * GA.w;   \
                f = up2((MW).z); ACC += f.x * GB.x + f.y * GB.y;   \
                f = up2((MW).w); ACC += f.x * GB.z + f.y * GB.w;   \
            } while (0)
#define DQ(ACC, Q)                                                           \
            do {                                                             \
                const uint4 m0 = *(const uint4*)(&M0Tp[(((Q)*4+0)*64+L)*8]); \
                const uint4 m1 = *(const uint4*)(&M0Tp[(((Q)*4+1)*64+L)*8]); \
                const uint4 m2 = *(const uint4*)(&M0Tp[(((Q)*4+2)*64+L)*8]); \
                const uint4 m3 = *(const uint4*)(&M0Tp[(((Q)*4+3)*64+L)*8]); \
                D8(ACC, m0, g0, g1); D8(ACC, m1, g2, g3);                    \
                D8(ACC, m2, g4, g5); D8(ACC, m3, g6, g7);                    \
            } while (0)
            DQ(d0, 0); DQ(d1, 1); DQ(d2, 2); DQ(d3, 3);
#undef DQ
#undef D8
            // rs2 = gw^T G gw over 64 lanes: col = L&31, k-half = L>>5
            float part = 0.f;
#define GS(U, ELO, EHI) part += G_l[gbase + 32 * (U)] * (hi ? (EHI) : (ELO));
            GS(0,  g0.x, g4.x) GS(1,  g0.y, g4.y) GS(2,  g0.z, g4.z)
            GS(3,  g0.w, g4.w) GS(4,  g1.x, g5.x) GS(5,  g1.y, g5.y)
            GS(6,  g1.z, g5.z) GS(7,  g1.w, g5.w) GS(8,  g2.x, g6.x)
            GS(9,  g2.y, g6.y) GS(10, g2.z, g6.z) GS(11, g2.w, g6.w)
            GS(12, g3.x, g7.x) GS(13, g3.y, g7.y) GS(14, g3.z, g7.z)
            GS(15, g3.w, g7.w)
#undef GS
            float rp = part * gwcol;
            rp = DPP_ADD(rp, 0x128);   // row_ror:8
            rp = DPP_ADD(rp, 0x124);   // row_ror:4
            rp = DPP_ADD(rp, 0x122);   // row_ror:2
            rp = DPP_ADD(rp, 0x121);   // row_ror:1
            rs2 = RDLANE(rp, 0) + RDLANE(rp, 16) +
                  RDLANE(rp, 32) + RDLANE(rp, 48);
        }
        const float inv_rs = 1.0f / fmaxf(sqrtf(rs2), EPS);

        // choices for the lane's 4 c's; local r-sum; 1 DPP pair-add -> gw[nc]
        float s4;
        {
            float cc0 = d0 * inv_rs * iw4.x; cc0 = fmaxf(cc0, 0.01f * cc0);
            float cc1 = d1 * inv_rs * iw4.y; cc1 = fmaxf(cc1, 0.01f * cc1);
            float cc2 = d2 * inv_rs * iw4.z; cc2 = fmaxf(cc2, 0.01f * cc2);
            float cc3 = d3 * inv_rs * iw4.w; cc3 = fmaxf(cc3, 0.01f * cc3);
            const float ch0 = fmaf(cc0, An.x, Bn.x) * i1c.x;
            const float ch1 = fmaf(cc1, An.y, Bn.y) * i1c.y;
            const float ch2 = fmaf(cc2, An.z, Bn.z) * i1c.z;
            const float ch3 = fmaf(cc3, An.w, Bn.w) * i1c.w;
            s4 = (ch0 + ch1) + (ch2 + ch3);
        }
        const float gwv = DPP_ADD(s4, 0xB1);   // quad_perm xor1: pair sum

        if ((L & 1) == 0) {
            const int nc = L >> 1;
            gw_l[s & 1][nc] = gwv;
            gws_g[((size_t)s * 256 + b) * 32 + nc] = gwv;
        }
        __syncthreads();
        i1c = i1n;
    }
}

// ---------------- K5: expand out[b,s,v] = Sv^T gw (unchanged) ----------------
__global__ void __launch_bounds__(256) expand_kernel(
    const float* __restrict__ gws_g, const float* __restrict__ sv_g,
    float* __restrict__ out)
{
    const int t = threadIdx.x;
    const int m0 = blockIdx.x * 32;
    __shared__ __align__(16) float SvT[256 * 36];
    __shared__ __align__(16) float gwl[32 * 32];

    for (int i = t; i < 8192; i += 256) {
        const int k = i >> 8, v = i & 255;
        SvT[v * 36 + k] = sv_g[i];
    }
    for (int i = t; i < 1024; i += 256)
        gwl[i] = gws_g[(size_t)m0 * 32 + i];
    __syncthreads();

#pragma unroll 4
    for (int r = 0; r < 32; ++r) {
        float acc = 0.f;
#pragma unroll
        for (int j = 0; j < 8; ++j) {
            const float4 g   = *(const float4*)(gwl + r * 32 + 4 * j);
            const float4 sv4 = *(const float4*)(SvT + t * 36 + 4 * j);
            acc += g.x * sv4.x + g.y * sv4.y + g.z * sv4.z + g.w * sv4.w;
        }
        const int m = m0 + r;
        const int s = m >> 8, bb = m & 255;
        out[((size_t)bb * 128 + s) * 256 + t] = acc;
    }
}

} // namespace

extern "C" void kernel_launch(void* const* d_in, const int* in_sizes, int n_in,
                              void* d_out, int out_size, void* d_ws, size_t ws_size,
                              hipStream_t stream) {
    (void)in_sizes; (void)n_in; (void)out_size; (void)ws_size;
    const float* av  = (const float*)d_in[0];
    const float* xnm = (const float*)d_in[1];
    const float* x   = (const float*)d_in[2];
    const float* ynm = (const float*)d_in[3];
    const float* y   = (const float*)d_in[4];
    const float* sv  = (const float*)d_in[5];
    const float* sw  = (const float*)d_in[6];
    const float* snw = (const float*)d_in[7];
    const float* def = (const float*)d_in[8];
    const float* vnw = (const float*)d_in[9];

    // ws: pxy f16 33.55MB | i1 f32 33.55MB | gws f32 4.19MB | smalls | M0Th f16
    __half* pxy = (__half*)d_ws;
    float*  i1  = (float*)((char*)d_ws + (size_t)33554432);
    float*  gws = i1 + 8388608;
    float*  sm  = gws + 1048576;
    float* M0T = sm;            // 8192
    float* PD  = M0T + 8192;    // 1024
    float* G   = PD + 1024;     // 1024
    float* w0s = G + 1024;      // 256
    float* iw0 = w0s + 256;
    float* iw1 = iw0 + 256;
    float* n0  = iw1 + 256;
    float* n1  = n0 + 256;
    __half* M0Th = (__half*)(n1 + 256);   // 8192 halfs, 16B-aligned

    prep_kernel<<<dim3(288), dim3(256), 0, stream>>>(
        sv, sw, snw, def, M0T, M0Th, PD, G, w0s, iw0, iw1, n0, n1);
    pxy_gemm<<<dim3(2048), dim3(256), 0, stream>>>(x, y, sw, pxy);
    finish_kernel<<<dim3(32768), dim3(256), 0, stream>>>(
        av, xnm, ynm, x, y, def, vnw, PD, iw1, n1, pxy, i1);
    scan_kernel<<<dim3(256), dim3(64), 0, stream>>>(
        i1, M0Th, G, w0s, iw0, n0, gws);
    expand_kernel<<<dim3(1024), dim3(256), 0, stream>>>(gws, sv, (float*)d_out);
}

// Round 10
// 291.714 us; speedup vs baseline: 6.8165x; 1.1403x over previous
//
#include <hip/hip_runtime.h>
#include <hip/hip_fp16.h>
#include <math.h>

// Round 10: LDS-free scan loop. Round 9 scan (128us, ~2400cy/step) re-read
// step-INVARIANT M0T (16 b128) + G (16 b32) + gw (9 reads) from LDS every
// step at ~120cy each with 1 wave/CU (zero TLP). Now:
//  - M0T in 32 named float4 VGPRs (f32, loaded once; budget 512 @ wpe(1)).
//  - gw broadcast via 32 v_readlane -> SGPRs (no LDS write/read, no barrier).
//  - G[k][L>>1] in 32 VGPRs; rp = h*gwv aligns with gwv layout (lanes 2k,2k+1
//    hold gw[k]) -> wave sum = 2*rs2; 4 DPP-ror + 4 readlane, *0.5.
//  - i1 prefetch depth 2 through named float4 regs.
// prep/pxy/finish/expand unchanged from round 9.

namespace {

constexpr float EPS = 1e-8f;

typedef _Float16 half8 __attribute__((ext_vector_type(8)));
typedef float    f32x4 __attribute__((ext_vector_type(4)));

__device__ __forceinline__ float sigmoidf_(float x) {
    return 1.0f / (1.0f + expf(-x));
}

#define RTREE64(p) do { \
    p += __shfl_xor(p, 32); p += __shfl_xor(p, 16); p += __shfl_xor(p, 8); \
    p += __shfl_xor(p, 4);  p += __shfl_xor(p, 2);  p += __shfl_xor(p, 1); } while (0)

#define DPP_ADD(x, CTRL) \
    ((x) + __int_as_float(__builtin_amdgcn_mov_dpp( \
        __float_as_int(x), (CTRL), 0xF, 0xF, true)))
#define RDLANE(x, L) \
    __int_as_float(__builtin_amdgcn_readlane(__float_as_int(x), (L)))

#define REP32(F) F(0) F(1) F(2) F(3) F(4) F(5) F(6) F(7) \
                 F(8) F(9) F(10) F(11) F(12) F(13) F(14) F(15) \
                 F(16) F(17) F(18) F(19) F(20) F(21) F(22) F(23) \
                 F(24) F(25) F(26) F(27) F(28) F(29) F(30) F(31)

// ---------------- K1: prep (unchanged) ----------------
__global__ void __launch_bounds__(256) prep_kernel(
    const float* __restrict__ sv, const float* __restrict__ sw,
    const float* __restrict__ snw, const float* __restrict__ def,
    float* __restrict__ M0T, __half* __restrict__ M0Th,
    float* __restrict__ PD, float* __restrict__ G,
    float* __restrict__ w0s, float* __restrict__ iw0, float* __restrict__ iw1,
    float* __restrict__ n0, float* __restrict__ n1)
{
    const int t = threadIdx.x, wave = t >> 6, lane = t & 63;
    __shared__ float wsum[39][4];

    if (blockIdx.x < 256) {
        const int c = blockIdx.x;
        const float w0v = sw[(size_t)c * 512 + t];
        const float w1v = sw[(size_t)c * 512 + 256 + t];
#pragma unroll
        for (int k = 0; k < 32; ++k) {
            float p = w0v * sv[k * 256 + t];
            RTREE64(p);
            if (lane == 0) wsum[k][wave] = p;
        }
#pragma unroll
        for (int j = 0; j < 4; ++j) {
            float p = w1v * def[j * 256 + t];
            RTREE64(p);
            if (lane == 0) wsum[32 + j][wave] = p;
        }
        {
            float p = w0v * w0v; RTREE64(p); if (lane == 0) wsum[36][wave] = p;
            float q = w1v * w1v; RTREE64(q); if (lane == 0) wsum[37][wave] = q;
            float r = w0v;       RTREE64(r); if (lane == 0) wsum[38][wave] = r;
        }
        __syncthreads();
        if (t < 32) {
            const float v = wsum[t][0] + wsum[t][1] + wsum[t][2] + wsum[t][3];
            M0T[t * 256 + c] = v;
            M0Th[c * 32 + t] = __float2half(v);
        } else if (t < 36) {
            PD[(t - 32) * 256 + c] =
                wsum[t][0] + wsum[t][1] + wsum[t][2] + wsum[t][3];
        } else if (t == 36) {
            iw0[c] = 1.0f / fmaxf(sqrtf(wsum[36][0] + wsum[36][1] +
                                        wsum[36][2] + wsum[36][3]), EPS);
        } else if (t == 37) {
            iw1[c] = 1.0f / fmaxf(sqrtf(wsum[37][0] + wsum[37][1] +
                                        wsum[37][2] + wsum[37][3]), EPS);
        } else if (t == 38) {
            w0s[c] = wsum[38][0] + wsum[38][1] + wsum[38][2] + wsum[38][3];
        } else if (t == 39) {
            n0[c] = sigmoidf_(snw[2 * c]);
        } else if (t == 40) {
            n1[c] = sigmoidf_(snw[2 * c + 1]);
        }
    } else {
        const int k = blockIdx.x - 256;
        const float svk = sv[k * 256 + t];
#pragma unroll
        for (int m = 0; m < 32; ++m) {
            float p = svk * sv[m * 256 + t];
            RTREE64(p);
            if (lane == 0) wsum[m][wave] = p;
        }
        __syncthreads();
        if (t < 32)
            G[k * 32 + t] = wsum[t][0] + wsum[t][1] + wsum[t][2] + wsum[t][3];
    }
}

// ---------------- K2: PXY GEMM via MFMA f16 (unchanged) ----------------
#define CVT8(dst, u, w)                                            \
    do {                                                           \
        dst[0] = (_Float16)u.x; dst[1] = (_Float16)u.y;            \
        dst[2] = (_Float16)u.z; dst[3] = (_Float16)u.w;            \
        dst[4] = (_Float16)w.x; dst[5] = (_Float16)w.y;            \
        dst[6] = (_Float16)w.z; dst[7] = (_Float16)w.w;            \
    } while (0)

__global__ void __launch_bounds__(256) pxy_gemm(
    const float* __restrict__ xv, const float* __restrict__ yv,
    const float* __restrict__ sw, __half* __restrict__ pxy)
{
    const int blk      = blockIdx.x;
    const int cstrip   = blk >> 8;
    const int rowblock = blk & 255;
    const int wid  = threadIdx.x >> 6;
    const int lane = threadIdx.x & 63;
    const int l16  = lane & 15;
    const int lhi  = lane >> 4;
    const bool isx = rowblock < 128;
    const float* __restrict__ A = isx ? xv : yv;
    const int row0   = (isx ? rowblock : rowblock - 128) * 256 + wid * 64;
    const int cbase  = cstrip * 32;
    const int colout = isx ? 0 : 256;

    const f32x4 z = {0.f, 0.f, 0.f, 0.f};
    f32x4 acc00 = z, acc01 = z, acc10 = z, acc11 = z;
    f32x4 acc20 = z, acc21 = z, acc30 = z, acc31 = z;

    const float* arow = A  + (size_t)(row0 + l16) * 256;
    const float* brow = sw + (size_t)(cbase + l16) * 512 + 256;

    for (int k0 = 0; k0 < 256; k0 += 32) {
        const int ka = k0 + lhi * 8;
        half8 a0, a1, a2, a3, b0, b1;
        { float4 u = *(const float4*)(arow + ka);
          float4 w = *(const float4*)(arow + ka + 4);            CVT8(a0, u, w); }
        { float4 u = *(const float4*)(arow + 16 * 256 + ka);
          float4 w = *(const float4*)(arow + 16 * 256 + ka + 4); CVT8(a1, u, w); }
        { float4 u = *(const float4*)(arow + 32 * 256 + ka);
          float4 w = *(const float4*)(arow + 32 * 256 + ka + 4); CVT8(a2, u, w); }
        { float4 u = *(const float4*)(arow + 48 * 256 + ka);
          float4 w = *(const float4*)(arow + 48 * 256 + ka + 4); CVT8(a3, u, w); }
        { float4 u = *(const float4*)(brow + ka);
          float4 w = *(const float4*)(brow + ka + 4);            CVT8(b0, u, w); }
        { float4 u = *(const float4*)(brow + 16 * 512 + ka);
          float4 w = *(const float4*)(brow + 16 * 512 + ka + 4); CVT8(b1, u, w); }
        acc00 = __builtin_amdgcn_mfma_f32_16x16x32_f16(a0, b0, acc00, 0, 0, 0);
        acc01 = __builtin_amdgcn_mfma_f32_16x16x32_f16(a0, b1, acc01, 0, 0, 0);
        acc10 = __builtin_amdgcn_mfma_f32_16x16x32_f16(a1, b0, acc10, 0, 0, 0);
        acc11 = __builtin_amdgcn_mfma_f32_16x16x32_f16(a1, b1, acc11, 0, 0, 0);
        acc20 = __builtin_amdgcn_mfma_f32_16x16x32_f16(a2, b0, acc20, 0, 0, 0);
        acc21 = __builtin_amdgcn_mfma_f32_16x16x32_f16(a2, b1, acc21, 0, 0, 0);
        acc30 = __builtin_amdgcn_mfma_f32_16x16x32_f16(a3, b0, acc30, 0, 0, 0);
        acc31 = __builtin_amdgcn_mfma_f32_16x16x32_f16(a3, b1, acc31, 0, 0, 0);
    }

    const size_t col = (size_t)colout + cbase + l16;
#pragma unroll
    for (int r = 0; r < 4; ++r) {
        const int rr = lhi * 4 + r;
        pxy[(size_t)(row0 +  0 + rr) * 512 + col]      = __float2half(acc00[r]);
        pxy[(size_t)(row0 +  0 + rr) * 512 + col + 16] = __float2half(acc01[r]);
        pxy[(size_t)(row0 + 16 + rr) * 512 + col]      = __float2half(acc10[r]);
        pxy[(size_t)(row0 + 16 + rr) * 512 + col + 16] = __float2half(acc11[r]);
        pxy[(size_t)(row0 + 32 + rr) * 512 + col]      = __float2half(acc20[r]);
        pxy[(size_t)(row0 + 32 + rr) * 512 + col + 16] = __float2half(acc21[r]);
        pxy[(size_t)(row0 + 48 + rr) * 512 + col]      = __float2half(acc30[r]);
        pxy[(size_t)(row0 + 48 + rr) * 512 + col + 16] = __float2half(acc31[r]);
    }
}

// ---------------- K3: finish — precompute i1[s,b,c] (unchanged) ----------------
__global__ void __launch_bounds__(256) finish_kernel(
    const float* __restrict__ av_g, const float* __restrict__ xn_g,
    const float* __restrict__ yn_g, const float* __restrict__ xv_g,
    const float* __restrict__ yv_g, const float* __restrict__ def_g,
    const float* __restrict__ vnw_g, const float* __restrict__ PD_g,
    const float* __restrict__ iw1_g, const float* __restrict__ n1_g,
    const __half* __restrict__ pxy, float* __restrict__ i1_g)
{
    const int m = blockIdx.x;
    const int t = threadIdx.x, wave = t >> 6, lane = t & 63;
    __shared__ float wsum[8][4];
    __shared__ float nwv_l[18];
    if (t < 18) nwv_l[t] = sigmoidf_(vnw_g[t]);

    const size_t base = (size_t)m * 256 + t;
    const float av = av_g[base], xn = xn_g[base], yn = yn_g[base];
    const float xv = xv_g[base], yv = yv_g[base];

    {
        float p0 = av * xn, p1 = av * yn, p2 = xn * yn;
        float p3 = av * av, p4 = xn * xn, p5 = yn * yn;
        RTREE64(p0); RTREE64(p1); RTREE64(p2);
        RTREE64(p3); RTREE64(p4); RTREE64(p5);
        if (lane == 0) {
            wsum[0][wave] = p0; wsum[1][wave] = p1; wsum[2][wave] = p2;
            wsum[3][wave] = p3; wsum[4][wave] = p4; wsum[5][wave] = p5;
        }
    }
    __syncthreads();
    const float axn = wsum[0][0] + wsum[0][1] + wsum[0][2] + wsum[0][3];
    const float ayn = wsum[1][0] + wsum[1][1] + wsum[1][2] + wsum[1][3];
    const float xny = wsum[2][0] + wsum[2][1] + wsum[2][2] + wsum[2][3];
    const float naa = wsum[3][0] + wsum[3][1] + wsum[3][2] + wsum[3][3];
    const float nxx = wsum[4][0] + wsum[4][1] + wsum[4][2] + wsum[4][3];
    const float nyy = wsum[5][0] + wsum[5][1] + wsum[5][2] + wsum[5][3];
    const float na = fmaxf(sqrtf(naa), EPS);
    const float nx = fmaxf(sqrtf(nxx), EPS);
    const float ny = fmaxf(sqrtf(nyy), EPS);
    float csarr[3];
    csarr[0] = axn / (na * nx);
    csarr[1] = ayn / (na * ny);
    csarr[2] = xny / (nx * ny);

    float vc[6];
#pragma unroll
    for (int jj = 0; jj < 6; ++jj) {
        float p = 1.0f;
#pragma unroll
        for (int k = 0; k < 3; ++k) {
            const float a = nwv_l[jj * 3 + k];
            const float csk = csarr[k];
            p = p * (a * csk + (1.0f - a) * (1.0f - csk));
        }
        vc[jj] = p;
    }

    const float val = vc[0] * xv + vc[1] * yv
                    + vc[2] * def_g[t]       + vc[3] * def_g[256 + t]
                    + vc[4] * def_g[512 + t] + vc[5] * def_g[768 + t];
    float qv = val * val;
    RTREE64(qv);
    if (lane == 0) wsum[7][wave] = qv;
    __syncthreads();
    const float inv_val = 1.0f / fmaxf(
        sqrtf(wsum[7][0] + wsum[7][1] + wsum[7][2] + wsum[7][3]), EPS);

    const float px = __half2float(pxy[(size_t)m * 512 + t]);
    const float py = __half2float(pxy[(size_t)m * 512 + 256 + t]);
    const float d1 = vc[0] * px + vc[1] * py
                   + vc[2] * PD_g[t]       + vc[3] * PD_g[256 + t]
                   + vc[4] * PD_g[512 + t] + vc[5] * PD_g[768 + t];
    float c1 = d1 * inv_val * iw1_g[t];
    c1 = (c1 > 0.f) ? c1 : 0.01f * c1;
    const float nn = n1_g[t];
    i1_g[(size_t)m * 256 + t] = nn * c1 + (1.0f - nn) * (1.0f - c1);
}

// ---------------- K4: the scan — LDS-free, register-resident ----------------
__global__ void __launch_bounds__(64)
__attribute__((amdgpu_waves_per_eu(1)))
scan_kernel(
    const float* __restrict__ i1_g, const float* __restrict__ M0T_g,
    const float* __restrict__ G_g, const float* __restrict__ w0s_g,
    const float* __restrict__ iw0_g, const float* __restrict__ n0_g,
    float* __restrict__ gws_g)
{
    const int b = blockIdx.x;
    const int L = threadIdx.x;              // owns c = 4L..4L+3
    const int mcol = L >> 1;                // G/h column (pairs share)

    // M0T in registers: V{k}.{x,y,z,w} = M0T[k][4L+0..3]   (fp32, 128 VGPR)
#define LV(K) const float4 V##K = *(const float4*)(M0T_g + (K) * 256 + 4 * L);
    REP32(LV)
#undef LV
    // G in registers: GK{k} = G[k][mcol]
#define LG(K) const float GK##K = G_g[(K) * 32 + mcol];
    REP32(LG)
#undef LG

    const float4 w0s4 = *(const float4*)(w0s_g + 4 * L);
    const float4 iw4  = *(const float4*)(iw0_g + 4 * L);
    const float4 n04  = *(const float4*)(n0_g + 4 * L);
    const float4 di = {1e-6f * w0s4.x, 1e-6f * w0s4.y,
                       1e-6f * w0s4.z, 1e-6f * w0s4.w};
    const float4 An = {2.f * n04.x - 1.f, 2.f * n04.y - 1.f,
                       2.f * n04.z - 1.f, 2.f * n04.w - 1.f};
    const float4 Bn = {1.f - n04.x, 1.f - n04.y, 1.f - n04.z, 1.f - n04.w};

    // i1 pipeline, prefetch depth 2
    float4 iA = *(const float4*)(i1_g + ((size_t)0 * 256 + b) * 256 + 4 * L);
    float4 iB = *(const float4*)(i1_g + ((size_t)1 * 256 + b) * 256 + 4 * L);
    float4 iC = *(const float4*)(i1_g + ((size_t)2 * 256 + b) * 256 + 4 * L);

    float gwv;   // loop-carried: lanes 2k,2k+1 hold gw[k]

#define NAND_GW(D0, D1, D2, D3, INV, IC)                              \
    do {                                                              \
        float cc0 = (D0) * (INV) * iw4.x; cc0 = fmaxf(cc0, 0.01f * cc0); \
        float cc1 = (D1) * (INV) * iw4.y; cc1 = fmaxf(cc1, 0.01f * cc1); \
        float cc2 = (D2) * (INV) * iw4.z; cc2 = fmaxf(cc2, 0.01f * cc2); \
        float cc3 = (D3) * (INV) * iw4.w; cc3 = fmaxf(cc3, 0.01f * cc3); \
        const float ch0 = fmaf(cc0, An.x, Bn.x) * (IC).x;             \
        const float ch1 = fmaf(cc1, An.y, Bn.y) * (IC).y;             \
        const float ch2 = fmaf(cc2, An.z, Bn.z) * (IC).z;             \
        const float ch3 = fmaf(cc3, An.w, Bn.w) * (IC).w;             \
        const float s4 = (ch0 + ch1) + (ch2 + ch3);                   \
        gwv = DPP_ADD(s4, 0xB1);  /* quad_perm xor1: pair sum */      \
    } while (0)

    // ---- step 0 ----
    {
        const float inv_rs = 1.0f / fmaxf(sqrtf(2.56e-10f), EPS);
        NAND_GW(di.x, di.y, di.z, di.w, inv_rs, iA);
        if ((L & 1) == 0) gws_g[(size_t)b * 32 + mcol] = gwv;
    }

    for (int s = 1; s < 128; ++s) {
        // prefetch i1 for step s+2 (consumed two iterations later)
        const int sp = (s + 2 < 128) ? s + 2 : 127;
        const float4 iN = *(const float4*)(
            i1_g + ((size_t)sp * 256 + b) * 256 + 4 * L);

        // broadcast gw -> 32 wave-uniform SGPRs
#define RL(K) const float sg##K = RDLANE(gwv, 2 * (K));
        REP32(RL)
#undef RL

        // d_q = sum_k M0T[k][c_q] * gw[k]   and   h = sum_k G[k][mcol]*gw[k]
        float d0 = 0.f, d1 = 0.f, d2 = 0.f, d3 = 0.f, h = 0.f;
#define STEP_K(K)                                   \
        d0 = fmaf(V##K.x, sg##K, d0);               \
        d1 = fmaf(V##K.y, sg##K, d1);               \
        d2 = fmaf(V##K.z, sg##K, d2);               \
        d3 = fmaf(V##K.w, sg##K, d3);               \
        h  = fmaf(GK##K, sg##K, h);
        REP32(STEP_K)
#undef STEP_K

        // rs2 = gw^T G gw: rp = h[mcol]*gw[mcol] (gwv layout matches),
        // wave sum = 2*rs2 (pairs duplicate)
        float rp = h * gwv;
        rp = DPP_ADD(rp, 0x128);   // row_ror:8
        rp = DPP_ADD(rp, 0x124);   // row_ror:4
        rp = DPP_ADD(rp, 0x122);   // row_ror:2
        rp = DPP_ADD(rp, 0x121);   // row_ror:1
        const float rs2 = 0.5f * (RDLANE(rp, 0) + RDLANE(rp, 16) +
                                  RDLANE(rp, 32) + RDLANE(rp, 48));
        const float inv_rs = 1.0f / fmaxf(sqrtf(rs2), EPS);

        NAND_GW(d0, d1, d2, d3, inv_rs, iB);
        if ((L & 1) == 0)
            gws_g[((size_t)s * 256 + b) * 32 + mcol] = gwv;

        iB = iC; iC = iN;
    }
#undef NAND_GW
}

// ---------------- K5: expand out[b,s,v] = Sv^T gw (unchanged) ----------------
__global__ void __launch_bounds__(256) expand_kernel(
    const float* __restrict__ gws_g, const float* __restrict__ sv_g,
    float* __restrict__ out)
{
    const int t = threadIdx.x;
    const int m0 = blockIdx.x * 32;
    __shared__ __align__(16) float SvT[256 * 36];
    __shared__ __align__(16) float gwl[32 * 32];

    for (int i = t; i < 8192; i += 256) {
        const int k = i >> 8, v = i & 255;
        SvT[v * 36 + k] = sv_g[i];
    }
    for (int i = t; i < 1024; i += 256)
        gwl[i] = gws_g[(size_t)m0 * 32 + i];
    __syncthreads();

#pragma unroll 4
    for (int r = 0; r < 32; ++r) {
        float acc = 0.f;
#pragma unroll
        for (int j = 0; j < 8; ++j) {
            const float4 g   = *(const float4*)(gwl + r * 32 + 4 * j);
            const float4 sv4 = *(const float4*)(SvT + t * 36 + 4 * j);
            acc += g.x * sv4.x + g.y * sv4.y + g.z * sv4.z + g.w * sv4.w;
        }
        const int m = m0 + r;
        const int s = m >> 8, bb = m & 255;
        out[((size_t)bb * 128 + s) * 256 + t] = acc;
    }
}

} // namespace

extern "C" void kernel_launch(void* const* d_in, const int* in_sizes, int n_in,
                              void* d_out, int out_size, void* d_ws, size_t ws_size,
                              hipStream_t stream) {
    (void)in_sizes; (void)n_in; (void)out_size; (void)ws_size;
    const float* av  = (const float*)d_in[0];
    const float* xnm = (const float*)d_in[1];
    const float* x   = (const float*)d_in[2];
    const float* ynm = (const float*)d_in[3];
    const float* y   = (const float*)d_in[4];
    const float* sv  = (const float*)d_in[5];
    const float* sw  = (const float*)d_in[6];
    const float* snw = (const float*)d_in[7];
    const float* def = (const float*)d_in[8];
    const float* vnw = (const float*)d_in[9];

    // ws: pxy f16 33.55MB | i1 f32 33.55MB | gws f32 4.19MB | smalls | M0Th f16
    __half* pxy = (__half*)d_ws;
    float*  i1  = (float*)((char*)d_ws + (size_t)33554432);
    float*  gws = i1 + 8388608;
    float*  sm  = gws + 1048576;
    float* M0T = sm;            // 8192
    float* PD  = M0T + 8192;    // 1024
    float* G   = PD + 1024;     // 1024
    float* w0s = G + 1024;      // 256
    float* iw0 = w0s + 256;
    float* iw1 = iw0 + 256;
    float* n0  = iw1 + 256;
    float* n1  = n0 + 256;
    __half* M0Th = (__half*)(n1 + 256);   // 8192 halfs, 16B-aligned

    prep_kernel<<<dim3(288), dim3(256), 0, stream>>>(
        sv, sw, snw, def, M0T, M0Th, PD, G, w0s, iw0, iw1, n0, n1);
    pxy_gemm<<<dim3(2048), dim3(256), 0, stream>>>(x, y, sw, pxy);
    finish_kernel<<<dim3(32768), dim3(256), 0, stream>>>(
        av, xnm, ynm, x, y, def, vnw, PD, iw1, n1, pxy, i1);
    scan_kernel<<<dim3(256), dim3(64), 0, stream>>>(
        i1, M0T, G, w0s, iw0, n0, gws);
    expand_kernel<<<dim3(1024), dim3(256), 0, stream>>>(gws, sv, (float*)d_out);
}

// Round 12
// 289.441 us; speedup vs baseline: 6.8701x; 1.0079x over previous
//
#include <hip/hip_runtime.h>
#include <hip/hip_fp16.h>
#include <math.h>

// Round 12: round 11 (XCD swizzle + pkrtz) failed to COMPILE only —
// __builtin_amdgcn_cvt_pkrtz returns __fp16 ext_vector(2), not _Float16.
// Fixed the union element type; logic identical to round 11:
//  - bijective XCD swizzle in pxy_gemm: all 8 col-strips of an A row-block
//    run consecutively on ONE XCD -> A L2-resident (was 3.3x HBM over-fetch).
//  - v_cvt_pkrtz packs 2 f32->2xf16 per VALU op (halves conversion cost).

namespace {

constexpr float EPS = 1e-8f;

typedef _Float16 half8  __attribute__((ext_vector_type(8)));
typedef __fp16   fp16x2 __attribute__((ext_vector_type(2)));
typedef float    f32x4  __attribute__((ext_vector_type(4)));

__device__ __forceinline__ float sigmoidf_(float x) {
    return 1.0f / (1.0f + expf(-x));
}

#define RTREE64(p) do { \
    p += __shfl_xor(p, 32); p += __shfl_xor(p, 16); p += __shfl_xor(p, 8); \
    p += __shfl_xor(p, 4);  p += __shfl_xor(p, 2);  p += __shfl_xor(p, 1); } while (0)

#define DPP_ADD(x, CTRL) \
    ((x) + __int_as_float(__builtin_amdgcn_mov_dpp( \
        __float_as_int(x), (CTRL), 0xF, 0xF, true)))
#define RDLANE(x, L) \
    __int_as_float(__builtin_amdgcn_readlane(__float_as_int(x), (L)))

#define REP32(F) F(0) F(1) F(2) F(3) F(4) F(5) F(6) F(7) \
                 F(8) F(9) F(10) F(11) F(12) F(13) F(14) F(15) \
                 F(16) F(17) F(18) F(19) F(20) F(21) F(22) F(23) \
                 F(24) F(25) F(26) F(27) F(28) F(29) F(30) F(31)

// ---------------- K1: prep (unchanged) ----------------
__global__ void __launch_bounds__(256) prep_kernel(
    const float* __restrict__ sv, const float* __restrict__ sw,
    const float* __restrict__ snw, const float* __restrict__ def,
    float* __restrict__ M0T, __half* __restrict__ M0Th,
    float* __restrict__ PD, float* __restrict__ G,
    float* __restrict__ w0s, float* __restrict__ iw0, float* __restrict__ iw1,
    float* __restrict__ n0, float* __restrict__ n1)
{
    const int t = threadIdx.x, wave = t >> 6, lane = t & 63;
    __shared__ float wsum[39][4];

    if (blockIdx.x < 256) {
        const int c = blockIdx.x;
        const float w0v = sw[(size_t)c * 512 + t];
        const float w1v = sw[(size_t)c * 512 + 256 + t];
#pragma unroll
        for (int k = 0; k < 32; ++k) {
            float p = w0v * sv[k * 256 + t];
            RTREE64(p);
            if (lane == 0) wsum[k][wave] = p;
        }
#pragma unroll
        for (int j = 0; j < 4; ++j) {
            float p = w1v * def[j * 256 + t];
            RTREE64(p);
            if (lane == 0) wsum[32 + j][wave] = p;
        }
        {
            float p = w0v * w0v; RTREE64(p); if (lane == 0) wsum[36][wave] = p;
            float q = w1v * w1v; RTREE64(q); if (lane == 0) wsum[37][wave] = q;
            float r = w0v;       RTREE64(r); if (lane == 0) wsum[38][wave] = r;
        }
        __syncthreads();
        if (t < 32) {
            const float v = wsum[t][0] + wsum[t][1] + wsum[t][2] + wsum[t][3];
            M0T[t * 256 + c] = v;
            M0Th[c * 32 + t] = __float2half(v);
        } else if (t < 36) {
            PD[(t - 32) * 256 + c] =
                wsum[t][0] + wsum[t][1] + wsum[t][2] + wsum[t][3];
        } else if (t == 36) {
            iw0[c] = 1.0f / fmaxf(sqrtf(wsum[36][0] + wsum[36][1] +
                                        wsum[36][2] + wsum[36][3]), EPS);
        } else if (t == 37) {
            iw1[c] = 1.0f / fmaxf(sqrtf(wsum[37][0] + wsum[37][1] +
                                        wsum[37][2] + wsum[37][3]), EPS);
        } else if (t == 38) {
            w0s[c] = wsum[38][0] + wsum[38][1] + wsum[38][2] + wsum[38][3];
        } else if (t == 39) {
            n0[c] = sigmoidf_(snw[2 * c]);
        } else if (t == 40) {
            n1[c] = sigmoidf_(snw[2 * c + 1]);
        }
    } else {
        const int k = blockIdx.x - 256;
        const float svk = sv[k * 256 + t];
#pragma unroll
        for (int m = 0; m < 32; ++m) {
            float p = svk * sv[m * 256 + t];
            RTREE64(p);
            if (lane == 0) wsum[m][wave] = p;
        }
        __syncthreads();
        if (t < 32)
            G[k * 32 + t] = wsum[t][0] + wsum[t][1] + wsum[t][2] + wsum[t][3];
    }
}

// ---------------- K2: PXY GEMM via MFMA f16 (XCD-swizzled + pkrtz) ----------------
#define CVT8(dst, u, w)                                            \
    do {                                                           \
        union { half8 v; fp16x2 p[4]; } cv;                        \
        cv.p[0] = __builtin_amdgcn_cvt_pkrtz((u).x, (u).y);        \
        cv.p[1] = __builtin_amdgcn_cvt_pkrtz((u).z, (u).w);        \
        cv.p[2] = __builtin_amdgcn_cvt_pkrtz((w).x, (w).y);        \
        cv.p[3] = __builtin_amdgcn_cvt_pkrtz((w).z, (w).w);        \
        dst = cv.v;                                                \
    } while (0)

__global__ void __launch_bounds__(256) pxy_gemm(
    const float* __restrict__ xv, const float* __restrict__ yv,
    const float* __restrict__ sw, __half* __restrict__ pxy)
{
    // bijective XCD swizzle: XCD = bid%8 gets logical blocks [x*256,(x+1)*256)
    // logical = rowblock*8 + cstrip -> all 8 col-strips of a row-block run on
    // ONE XCD, back-to-back -> A rows fetched once into that XCD's L2.
    const int swz      = (blockIdx.x & 7) * 256 + (blockIdx.x >> 3);
    const int cstrip   = swz & 7;            // 0..7
    const int rowblock = swz >> 3;           // 0..255
    const int wid  = threadIdx.x >> 6;
    const int lane = threadIdx.x & 63;
    const int l16  = lane & 15;
    const int lhi  = lane >> 4;
    const bool isx = rowblock < 128;
    const float* __restrict__ A = isx ? xv : yv;
    const int row0   = (isx ? rowblock : rowblock - 128) * 256 + wid * 64;
    const int cbase  = cstrip * 32;
    const int colout = isx ? 0 : 256;

    const f32x4 z = {0.f, 0.f, 0.f, 0.f};
    f32x4 acc00 = z, acc01 = z, acc10 = z, acc11 = z;
    f32x4 acc20 = z, acc21 = z, acc30 = z, acc31 = z;

    const float* arow = A  + (size_t)(row0 + l16) * 256;
    const float* brow = sw + (size_t)(cbase + l16) * 512 + 256;

    for (int k0 = 0; k0 < 256; k0 += 32) {
        const int ka = k0 + lhi * 8;
        half8 a0, a1, a2, a3, b0, b1;
        { float4 u = *(const float4*)(arow + ka);
          float4 w = *(const float4*)(arow + ka + 4);            CVT8(a0, u, w); }
        { float4 u = *(const float4*)(arow + 16 * 256 + ka);
          float4 w = *(const float4*)(arow + 16 * 256 + ka + 4); CVT8(a1, u, w); }
        { float4 u = *(const float4*)(arow + 32 * 256 + ka);
          float4 w = *(const float4*)(arow + 32 * 256 + ka + 4); CVT8(a2, u, w); }
        { float4 u = *(const float4*)(arow + 48 * 256 + ka);
          float4 w = *(const float4*)(arow + 48 * 256 + ka + 4); CVT8(a3, u, w); }
        { float4 u = *(const float4*)(brow + ka);
          float4 w = *(const float4*)(brow + ka + 4);            CVT8(b0, u, w); }
        { float4 u = *(const float4*)(brow + 16 * 512 + ka);
          float4 w = *(const float4*)(brow + 16 * 512 + ka + 4); CVT8(b1, u, w); }
        acc00 = __builtin_amdgcn_mfma_f32_16x16x32_f16(a0, b0, acc00, 0, 0, 0);
        acc01 = __builtin_amdgcn_mfma_f32_16x16x32_f16(a0, b1, acc01, 0, 0, 0);
        acc10 = __builtin_amdgcn_mfma_f32_16x16x32_f16(a1, b0, acc10, 0, 0, 0);
        acc11 = __builtin_amdgcn_mfma_f32_16x16x32_f16(a1, b1, acc11, 0, 0, 0);
        acc20 = __builtin_amdgcn_mfma_f32_16x16x32_f16(a2, b0, acc20, 0, 0, 0);
        acc21 = __builtin_amdgcn_mfma_f32_16x16x32_f16(a2, b1, acc21, 0, 0, 0);
        acc30 = __builtin_amdgcn_mfma_f32_16x16x32_f16(a3, b0, acc30, 0, 0, 0);
        acc31 = __builtin_amdgcn_mfma_f32_16x16x32_f16(a3, b1, acc31, 0, 0, 0);
    }

    const size_t col = (size_t)colout + cbase + l16;
#pragma unroll
    for (int r = 0; r < 4; ++r) {
        const int rr = lhi * 4 + r;
        pxy[(size_t)(row0 +  0 + rr) * 512 + col]      = __float2half(acc00[r]);
        pxy[(size_t)(row0 +  0 + rr) * 512 + col + 16] = __float2half(acc01[r]);
        pxy[(size_t)(row0 + 16 + rr) * 512 + col]      = __float2half(acc10[r]);
        pxy[(size_t)(row0 + 16 + rr) * 512 + col + 16] = __float2half(acc11[r]);
        pxy[(size_t)(row0 + 32 + rr) * 512 + col]      = __float2half(acc20[r]);
        pxy[(size_t)(row0 + 32 + rr) * 512 + col + 16] = __float2half(acc21[r]);
        pxy[(size_t)(row0 + 48 + rr) * 512 + col]      = __float2half(acc30[r]);
        pxy[(size_t)(row0 + 48 + rr) * 512 + col + 16] = __float2half(acc31[r]);
    }
}

// ---------------- K3: finish — precompute i1[s,b,c] (unchanged) ----------------
__global__ void __launch_bounds__(256) finish_kernel(
    const float* __restrict__ av_g, const float* __restrict__ xn_g,
    const float* __restrict__ yn_g, const float* __restrict__ xv_g,
    const float* __restrict__ yv_g, const float* __restrict__ def_g,
    const float* __restrict__ vnw_g, const float* __restrict__ PD_g,
    const float* __restrict__ iw1_g, const float* __restrict__ n1_g,
    const __half* __restrict__ pxy, float* __restrict__ i1_g)
{
    const int m = blockIdx.x;
    const int t = threadIdx.x, wave = t >> 6, lane = t & 63;
    __shared__ float wsum[8][4];
    __shared__ float nwv_l[18];
    if (t < 18) nwv_l[t] = sigmoidf_(vnw_g[t]);

    const size_t base = (size_t)m * 256 + t;
    const float av = av_g[base], xn = xn_g[base], yn = yn_g[base];
    const float xv = xv_g[base], yv = yv_g[base];

    {
        float p0 = av * xn, p1 = av * yn, p2 = xn * yn;
        float p3 = av * av, p4 = xn * xn, p5 = yn * yn;
        RTREE64(p0); RTREE64(p1); RTREE64(p2);
        RTREE64(p3); RTREE64(p4); RTREE64(p5);
        if (lane == 0) {
            wsum[0][wave] = p0; wsum[1][wave] = p1; wsum[2][wave] = p2;
            wsum[3][wave] = p3; wsum[4][wave] = p4; wsum[5][wave] = p5;
        }
    }
    __syncthreads();
    const float axn = wsum[0][0] + wsum[0][1] + wsum[0][2] + wsum[0][3];
    const float ayn = wsum[1][0] + wsum[1][1] + wsum[1][2] + wsum[1][3];
    const float xny = wsum[2][0] + wsum[2][1] + wsum[2][2] + wsum[2][3];
    const float naa = wsum[3][0] + wsum[3][1] + wsum[3][2] + wsum[3][3];
    const float nxx = wsum[4][0] + wsum[4][1] + wsum[4][2] + wsum[4][3];
    const float nyy = wsum[5][0] + wsum[5][1] + wsum[5][2] + wsum[5][3];
    const float na = fmaxf(sqrtf(naa), EPS);
    const float nx = fmaxf(sqrtf(nxx), EPS);
    const float ny = fmaxf(sqrtf(nyy), EPS);
    float csarr[3];
    csarr[0] = axn / (na * nx);
    csarr[1] = ayn / (na * ny);
    csarr[2] = xny / (nx * ny);

    float vc[6];
#pragma unroll
    for (int jj = 0; jj < 6; ++jj) {
        float p = 1.0f;
#pragma unroll
        for (int k = 0; k < 3; ++k) {
            const float a = nwv_l[jj * 3 + k];
            const float csk = csarr[k];
            p = p * (a * csk + (1.0f - a) * (1.0f - csk));
        }
        vc[jj] = p;
    }

    const float val = vc[0] * xv + vc[1] * yv
                    + vc[2] * def_g[t]       + vc[3] * def_g[256 + t]
                    + vc[4] * def_g[512 + t] + vc[5] * def_g[768 + t];
    float qv = val * val;
    RTREE64(qv);
    if (lane == 0) wsum[7][wave] = qv;
    __syncthreads();
    const float inv_val = 1.0f / fmaxf(
        sqrtf(wsum[7][0] + wsum[7][1] + wsum[7][2] + wsum[7][3]), EPS);

    const float px = __half2float(pxy[(size_t)m * 512 + t]);
    const float py = __half2float(pxy[(size_t)m * 512 + 256 + t]);
    const float d1 = vc[0] * px + vc[1] * py
                   + vc[2] * PD_g[t]       + vc[3] * PD_g[256 + t]
                   + vc[4] * PD_g[512 + t] + vc[5] * PD_g[768 + t];
    float c1 = d1 * inv_val * iw1_g[t];
    c1 = (c1 > 0.f) ? c1 : 0.01f * c1;
    const float nn = n1_g[t];
    i1_g[(size_t)m * 256 + t] = nn * c1 + (1.0f - nn) * (1.0f - c1);
}

// ---------------- K4: the scan — LDS-free, register-resident (unchanged) ----------------
__global__ void __launch_bounds__(64)
__attribute__((amdgpu_waves_per_eu(1)))
scan_kernel(
    const float* __restrict__ i1_g, const float* __restrict__ M0T_g,
    const float* __restrict__ G_g, const float* __restrict__ w0s_g,
    const float* __restrict__ iw0_g, const float* __restrict__ n0_g,
    float* __restrict__ gws_g)
{
    const int b = blockIdx.x;
    const int L = threadIdx.x;              // owns c = 4L..4L+3
    const int mcol = L >> 1;                // G/h column (pairs share)

#define LV(K) const float4 V##K = *(const float4*)(M0T_g + (K) * 256 + 4 * L);
    REP32(LV)
#undef LV
#define LG(K) const float GK##K = G_g[(K) * 32 + mcol];
    REP32(LG)
#undef LG

    const float4 w0s4 = *(const float4*)(w0s_g + 4 * L);
    const float4 iw4  = *(const float4*)(iw0_g + 4 * L);
    const float4 n04  = *(const float4*)(n0_g + 4 * L);
    const float4 di = {1e-6f * w0s4.x, 1e-6f * w0s4.y,
                       1e-6f * w0s4.z, 1e-6f * w0s4.w};
    const float4 An = {2.f * n04.x - 1.f, 2.f * n04.y - 1.f,
                       2.f * n04.z - 1.f, 2.f * n04.w - 1.f};
    const float4 Bn = {1.f - n04.x, 1.f - n04.y, 1.f - n04.z, 1.f - n04.w};

    float4 iA = *(const float4*)(i1_g + ((size_t)0 * 256 + b) * 256 + 4 * L);
    float4 iB = *(const float4*)(i1_g + ((size_t)1 * 256 + b) * 256 + 4 * L);
    float4 iC = *(const float4*)(i1_g + ((size_t)2 * 256 + b) * 256 + 4 * L);

    float gwv;   // loop-carried: lanes 2k,2k+1 hold gw[k]

#define NAND_GW(D0, D1, D2, D3, INV, IC)                              \
    do {                                                              \
        float cc0 = (D0) * (INV) * iw4.x; cc0 = fmaxf(cc0, 0.01f * cc0); \
        float cc1 = (D1) * (INV) * iw4.y; cc1 = fmaxf(cc1, 0.01f * cc1); \
        float cc2 = (D2) * (INV) * iw4.z; cc2 = fmaxf(cc2, 0.01f * cc2); \
        float cc3 = (D3) * (INV) * iw4.w; cc3 = fmaxf(cc3, 0.01f * cc3); \
        const float ch0 = fmaf(cc0, An.x, Bn.x) * (IC).x;             \
        const float ch1 = fmaf(cc1, An.y, Bn.y) * (IC).y;             \
        const float ch2 = fmaf(cc2, An.z, Bn.z) * (IC).z;             \
        const float ch3 = fmaf(cc3, An.w, Bn.w) * (IC).w;             \
        const float s4 = (ch0 + ch1) + (ch2 + ch3);                   \
        gwv = DPP_ADD(s4, 0xB1);  /* quad_perm xor1: pair sum */      \
    } while (0)

    // ---- step 0 ----
    {
        const float inv_rs = 1.0f / fmaxf(sqrtf(2.56e-10f), EPS);
        NAND_GW(di.x, di.y, di.z, di.w, inv_rs, iA);
        if ((L & 1) == 0) gws_g[(size_t)b * 32 + mcol] = gwv;
    }

    for (int s = 1; s < 128; ++s) {
        const int sp = (s + 2 < 128) ? s + 2 : 127;
        const float4 iN = *(const float4*)(
            i1_g + ((size_t)sp * 256 + b) * 256 + 4 * L);

#define RL(K) const float sg##K = RDLANE(gwv, 2 * (K));
        REP32(RL)
#undef RL

        float d0 = 0.f, d1 = 0.f, d2 = 0.f, d3 = 0.f, h = 0.f;
#define STEP_K(K)                                   \
        d0 = fmaf(V##K.x, sg##K, d0);               \
        d1 = fmaf(V##K.y, sg##K, d1);               \
        d2 = fmaf(V##K.z, sg##K, d2);               \
        d3 = fmaf(V##K.w, sg##K, d3);               \
        h  = fmaf(GK##K, sg##K, h);
        REP32(STEP_K)
#undef STEP_K

        float rp = h * gwv;
        rp = DPP_ADD(rp, 0x128);   // row_ror:8
        rp = DPP_ADD(rp, 0x124);   // row_ror:4
        rp = DPP_ADD(rp, 0x122);   // row_ror:2
        rp = DPP_ADD(rp, 0x121);   // row_ror:1
        const float rs2 = 0.5f * (RDLANE(rp, 0) + RDLANE(rp, 16) +
                                  RDLANE(rp, 32) + RDLANE(rp, 48));
        const float inv_rs = 1.0f / fmaxf(sqrtf(rs2), EPS);

        NAND_GW(d0, d1, d2, d3, inv_rs, iB);
        if ((L & 1) == 0)
            gws_g[((size_t)s * 256 + b) * 32 + mcol] = gwv;

        iB = iC; iC = iN;
    }
#undef NAND_GW
}

// ---------------- K5: expand out[b,s,v] = Sv^T gw (unchanged) ----------------
__global__ void __launch_bounds__(256) expand_kernel(
    const float* __restrict__ gws_g, const float* __restrict__ sv_g,
    float* __restrict__ out)
{
    const int t = threadIdx.x;
    const int m0 = blockIdx.x * 32;
    __shared__ __align__(16) float SvT[256 * 36];
    __shared__ __align__(16) float gwl[32 * 32];

    for (int i = t; i < 8192; i += 256) {
        const int k = i >> 8, v = i & 255;
        SvT[v * 36 + k] = sv_g[i];
    }
    for (int i = t; i < 1024; i += 256)
        gwl[i] = gws_g[(size_t)m0 * 32 + i];
    __syncthreads();

#pragma unroll 4
    for (int r = 0; r < 32; ++r) {
        float acc = 0.f;
#pragma unroll
        for (int j = 0; j < 8; ++j) {
            const float4 g   = *(const float4*)(gwl + r * 32 + 4 * j);
            const float4 sv4 = *(const float4*)(SvT + t * 36 + 4 * j);
            acc += g.x * sv4.x + g.y * sv4.y + g.z * sv4.z + g.w * sv4.w;
        }
        const int m = m0 + r;
        const int s = m >> 8, bb = m & 255;
        out[((size_t)bb * 128 + s) * 256 + t] = acc;
    }
}

} // namespace

extern "C" void kernel_launch(void* const* d_in, const int* in_sizes, int n_in,
                              void* d_out, int out_size, void* d_ws, size_t ws_size,
                              hipStream_t stream) {
    (void)in_sizes; (void)n_in; (void)out_size; (void)ws_size;
    const float* av  = (const float*)d_in[0];
    const float* xnm = (const float*)d_in[1];
    const float* x   = (const float*)d_in[2];
    const float* ynm = (const float*)d_in[3];
    const float* y   = (const float*)d_in[4];
    const float* sv  = (const float*)d_in[5];
    const float* sw  = (const float*)d_in[6];
    const float* snw = (const float*)d_in[7];
    const float* def = (const float*)d_in[8];
    const float* vnw = (const float*)d_in[9];

    // ws: pxy f16 33.55MB | i1 f32 33.55MB | gws f32 4.19MB | smalls | M0Th f16
    __half* pxy = (__half*)d_ws;
    float*  i1  = (float*)((char*)d_ws + (size_t)33554432);
    float*  gws = i1 + 8388608;
    float*  sm  = gws + 1048576;
    float* M0T = sm;            // 8192
    float* PD  = M0T + 8192;    // 1024
    float* G   = PD + 1024;     // 1024
    float* w0s = G + 1024;      // 256
    float* iw0 = w0s + 256;
    float* iw1 = iw0 + 256;
    float* n0  = iw1 + 256;
    float* n1  = n0 + 256;
    __half* M0Th = (__half*)(n1 + 256);   // 8192 halfs, 16B-aligned

    prep_kernel<<<dim3(288), dim3(256), 0, stream>>>(
        sv, sw, snw, def, M0T, M0Th, PD, G, w0s, iw0, iw1, n0, n1);
    pxy_gemm<<<dim3(2048), dim3(256), 0, stream>>>(x, y, sw, pxy);
    finish_kernel<<<dim3(32768), dim3(256), 0, stream>>>(
        av, xnm, ynm, x, y, def, vnw, PD, iw1, n1, pxy, i1);
    scan_kernel<<<dim3(256), dim3(64), 0, stream>>>(
        i1, M0T, G, w0s, iw0, n0, gws);
    expand_kernel<<<dim3(1024), dim3(256), 0, stream>>>(gws, sv, (float*)d_out);
}